// Round 6
// baseline (567.248 us; speedup 1.0000x reference)
//
#include <hip/hip_runtime.h>
#include <hip/hip_bf16.h>

#define N_NODES 4096
#define E_EDGES 65536
#define IN_F    512
#define H_F     256
#define QD      256
#define NHEAD   8
#define HD      32
#define OUT_F   10
#define L_LAYERS 2
#define CT_N    50

enum { FLAG_RELU = 1, FLAG_ACCUM = 2, FLAG_WF32 = 4, FLAG_WB16 = 8 };

typedef __attribute__((ext_vector_type(8))) __bf16 bf16x8;
typedef __attribute__((ext_vector_type(4))) float f32x4;

union PU { bf16x8 v; __hip_bfloat16 h[8]; __hip_bfloat162 b2[4]; };

// ---------------------------------------------------------------------------
// bf16 MFMA GEMM.  A: bf16 [M][K] row-major (lda).  B: bf16 [N][K] (B^T layout).
// ---------------------------------------------------------------------------
template<int BM, int BN, bool EDGE>
__global__ __launch_bounds__(256) void gemm_mfma(
    const __hip_bfloat16* __restrict__ A, int lda,
    const __hip_bfloat16* __restrict__ B, int ldb,
    float* __restrict__ Cf, __hip_bfloat16* __restrict__ Cb, int ldc,
    int K,
    const float* __restrict__ bias, const float* __restrict__ rowscale,
    const int* __restrict__ tgtp, const int* __restrict__ srcp,
    const float* __restrict__ kbias,
    int flags)
{
    constexpr int WM = BM / 2, WN = BN / 2, MT = WM / 16, NT = WN / 16;
    constexpr int LDT = 40;   // 80B row stride -> max 2-way bank alias (free, m136)
    __shared__ alignas(16) __hip_bfloat16 As[BM * LDT];
    __shared__ alignas(16) __hip_bfloat16 Bs[BN * LDT];

    const int tid = threadIdx.x;
    const int w = tid >> 6, lane = tid & 63, l16 = lane & 15, quad = lane >> 4;
    const int wm = w >> 1, wn = w & 1;
    const int bm = blockIdx.y * BM, bn = blockIdx.x * BN;

    f32x4 acc[MT][NT];
    #pragma unroll
    for (int i = 0; i < MT; ++i)
        #pragma unroll
        for (int j = 0; j < NT; ++j)
            #pragma unroll
            for (int r = 0; r < 4; ++r) acc[i][j][r] = 0.f;

    for (int k0 = 0; k0 < K; k0 += 32) {
        #pragma unroll
        for (int f = tid; f < BM * 4; f += 256) {
            int r = f >> 2, sg = f & 3;
            if (EDGE) {
                int i = bm + r;
                int tg = tgtp[i], sr = srcp[i];
                PU z1, z2, o;
                z1.v = *reinterpret_cast<const bf16x8*>(A + (size_t)tg * 512 + k0 + sg * 8);
                z2.v = *reinterpret_cast<const bf16x8*>(A + (size_t)sr * 512 + 256 + k0 + sg * 8);
                float4 b0 = *reinterpret_cast<const float4*>(kbias + k0 + sg * 8);
                float4 b1 = *reinterpret_cast<const float4*>(kbias + k0 + sg * 8 + 4);
                float bb[8] = {b0.x, b0.y, b0.z, b0.w, b1.x, b1.y, b1.z, b1.w};
                #pragma unroll
                for (int j = 0; j < 8; ++j) {
                    float v = __bfloat162float(z1.h[j]) + __bfloat162float(z2.h[j]) + bb[j];
                    o.h[j] = __float2bfloat16(fmaxf(v, 0.f));
                }
                *reinterpret_cast<bf16x8*>(&As[r * LDT + sg * 8]) = o.v;
            } else {
                *reinterpret_cast<uint4*>(&As[r * LDT + sg * 8]) =
                    *reinterpret_cast<const uint4*>(A + (size_t)(bm + r) * lda + k0 + sg * 8);
            }
        }
        #pragma unroll
        for (int f = tid; f < BN * 4; f += 256) {
            int r = f >> 2, sg = f & 3;
            *reinterpret_cast<uint4*>(&Bs[r * LDT + sg * 8]) =
                *reinterpret_cast<const uint4*>(B + (size_t)(bn + r) * ldb + k0 + sg * 8);
        }
        __syncthreads();
        bf16x8 af[MT], bfr[NT];
        #pragma unroll
        for (int mt = 0; mt < MT; ++mt)
            af[mt] = *reinterpret_cast<const bf16x8*>(&As[(wm * WM + mt * 16 + l16) * LDT + quad * 8]);
        #pragma unroll
        for (int nt = 0; nt < NT; ++nt)
            bfr[nt] = *reinterpret_cast<const bf16x8*>(&Bs[(wn * WN + nt * 16 + l16) * LDT + quad * 8]);
        #pragma unroll
        for (int mt = 0; mt < MT; ++mt)
            #pragma unroll
            for (int nt = 0; nt < NT; ++nt)
                acc[mt][nt] = __builtin_amdgcn_mfma_f32_16x16x32_bf16(af[mt], bfr[nt], acc[mt][nt], 0, 0, 0);
        __syncthreads();
    }

    #pragma unroll
    for (int mt = 0; mt < MT; ++mt) {
        #pragma unroll
        for (int nt = 0; nt < NT; ++nt) {
            int col = bn + wn * WN + nt * 16 + l16;
            #pragma unroll
            for (int r = 0; r < 4; ++r) {
                int row = bm + wm * WM + mt * 16 + quad * 4 + r;
                float v = acc[mt][nt][r];
                if (bias) {
                    float bv = bias[col];
                    if (rowscale) bv *= rowscale[row];
                    v += bv;
                }
                if (flags & FLAG_RELU) v = fmaxf(v, 0.f);
                size_t off = (size_t)row * ldc + col;
                if (flags & FLAG_ACCUM)     Cf[off] += v;
                else if (flags & FLAG_WF32) Cf[off] = v;
                if (flags & FLAG_WB16)      Cb[off] = __float2bfloat16(v);
            }
        }
    }
}

// ---------------------------------------------------------------------------
// Specialized edge-MLP GEMM: M2 = relu(relu(Z[tgt][:256]+Z[src][256:]+bm1) @ Wm2 + bm2)
// Full-K gather-once into LDS.  BM=64, BN=256.  512 threads.
// ---------------------------------------------------------------------------
__global__ __launch_bounds__(512) void edge_gemm(
    const __hip_bfloat16* __restrict__ Z,   // [N][512] bf16 (Z12)
    const __hip_bfloat16* __restrict__ B,   // Wm2^T [256][256] bf16
    __hip_bfloat16* __restrict__ C,         // M216 [E][256] bf16
    const int* __restrict__ tgtp, const int* __restrict__ srcp,
    const float* __restrict__ kbias,        // bm1 [256]
    const float* __restrict__ bias)         // bm2 [256]
{
    constexpr int LDA = 264;   // 256 + 8 pad
    constexpr int LDB = 40;
    __shared__ alignas(16) __hip_bfloat16 As[64 * LDA];    // 33,792 B
    __shared__ alignas(16) __hip_bfloat16 Bs[256 * LDB];   // 20,480 B

    const int tid = threadIdx.x;
    const int w = tid >> 6, lane = tid & 63, l16 = lane & 15, quad = lane >> 4;
    // XCD-aware swizzle: nwg=1024, divisible by 8 -> bijective
    const int bid = blockIdx.x;
    const int bm = ((bid & 7) * 128 + (bid >> 3)) * 64;

    // ---- phase 1: gather full-K M1 rows into registers ----
    bf16x8 zt[4], zs[4];
    #pragma unroll
    for (int u = 0; u < 4; ++u) {
        int g = u * 512 + tid;           // [0, 2048): 64 rows x 32 chunks(16B)
        int r = g >> 5, c = g & 31;
        int i = bm + r;
        int tg = tgtp[i], sr = srcp[i];
        zt[u] = *reinterpret_cast<const bf16x8*>(Z + (size_t)tg * 512 + c * 8);
        zs[u] = *reinterpret_cast<const bf16x8*>(Z + (size_t)sr * 512 + 256 + c * 8);
    }
    // ---- phase 2: fuse (add + bm1 + relu), write As ----
    #pragma unroll
    for (int u = 0; u < 4; ++u) {
        int g = u * 512 + tid;
        int r = g >> 5, c = g & 31;
        PU a, b, o;
        a.v = zt[u]; b.v = zs[u];
        float4 k0v = *reinterpret_cast<const float4*>(kbias + c * 8);
        float4 k1v = *reinterpret_cast<const float4*>(kbias + c * 8 + 4);
        float bb[8] = {k0v.x, k0v.y, k0v.z, k0v.w, k1v.x, k1v.y, k1v.z, k1v.w};
        #pragma unroll
        for (int j = 0; j < 8; ++j) {
            float v = __bfloat162float(a.h[j]) + __bfloat162float(b.h[j]) + bb[j];
            o.h[j] = __float2bfloat16(fmaxf(v, 0.f));
        }
        *reinterpret_cast<bf16x8*>(&As[r * LDA + c * 8]) = o.v;
    }

    const int wn = w;
    f32x4 acc[4][2];
    #pragma unroll
    for (int mt = 0; mt < 4; ++mt)
        #pragma unroll
        for (int nt = 0; nt < 2; ++nt)
            #pragma unroll
            for (int r = 0; r < 4; ++r) acc[mt][nt][r] = 0.f;

    for (int k0 = 0; k0 < 256; k0 += 32) {
        #pragma unroll
        for (int u = 0; u < 2; ++u) {
            int f = u * 512 + tid;
            int r = f >> 2, sg = f & 3;
            *reinterpret_cast<uint4*>(&Bs[r * LDB + sg * 8]) =
                *reinterpret_cast<const uint4*>(B + (size_t)r * 256 + k0 + sg * 8);
        }
        __syncthreads();
        bf16x8 af[4], bfr[2];
        #pragma unroll
        for (int mt = 0; mt < 4; ++mt)
            af[mt] = *reinterpret_cast<const bf16x8*>(&As[(mt * 16 + l16) * LDA + k0 + quad * 8]);
        #pragma unroll
        for (int nt = 0; nt < 2; ++nt)
            bfr[nt] = *reinterpret_cast<const bf16x8*>(&Bs[(wn * 32 + nt * 16 + l16) * LDB + quad * 8]);
        #pragma unroll
        for (int mt = 0; mt < 4; ++mt)
            #pragma unroll
            for (int nt = 0; nt < 2; ++nt)
                acc[mt][nt] = __builtin_amdgcn_mfma_f32_16x16x32_bf16(af[mt], bfr[nt], acc[mt][nt], 0, 0, 0);
        __syncthreads();
    }

    #pragma unroll
    for (int mt = 0; mt < 4; ++mt) {
        #pragma unroll
        for (int nt = 0; nt < 2; ++nt) {
            int col = wn * 32 + nt * 16 + l16;
            float bv = bias[col];
            #pragma unroll
            for (int r = 0; r < 4; ++r) {
                int row = bm + mt * 16 + quad * 4 + r;
                float v = fmaxf(acc[mt][nt][r] + bv, 0.f);
                C[(size_t)row * 256 + col] = __float2bfloat16(v);
            }
        }
    }
}

// ---------------------------------------------------------------------------
// Batched (grid.z) 64x64 GEMM slices: M=4096, N=256 (per slice), K=256, ldb=256.
// ---------------------------------------------------------------------------
struct GSet { const __hip_bfloat16* A; int lda; const __hip_bfloat16* B;
              const float* bias; const float* rowscale;
              const float* extra; float esc; float cscale;
              __hip_bfloat16* C; float* Cf; int vtout; int ldc; int coloff; };
struct GPack { GSet s[8]; };

__global__ __launch_bounds__(256) void gemm_bz(GPack p, const int* __restrict__ eidx)
{
    GSet g = p.s[blockIdx.z];
    constexpr int LDT = 40;
    __shared__ alignas(16) __hip_bfloat16 As[64 * LDT];
    __shared__ alignas(16) __hip_bfloat16 Bs[64 * LDT];

    const int tid = threadIdx.x;
    const int w = tid >> 6, lane = tid & 63, l16 = lane & 15, quad = lane >> 4;
    const int wm = w >> 1, wn = w & 1;
    const int bm = blockIdx.y * 64, bn = blockIdx.x * 64;

    f32x4 acc[2][2];
    #pragma unroll
    for (int i = 0; i < 2; ++i)
        #pragma unroll
        for (int j = 0; j < 2; ++j)
            #pragma unroll
            for (int r = 0; r < 4; ++r) acc[i][j][r] = 0.f;

    for (int k0 = 0; k0 < 256; k0 += 32) {
        #pragma unroll
        for (int f = tid; f < 256; f += 256) {
            int r = f >> 2, sg = f & 3;
            *reinterpret_cast<uint4*>(&As[r * LDT + sg * 8]) =
                *reinterpret_cast<const uint4*>(g.A + (size_t)(bm + r) * g.lda + k0 + sg * 8);
            *reinterpret_cast<uint4*>(&Bs[r * LDT + sg * 8]) =
                *reinterpret_cast<const uint4*>(g.B + (size_t)(bn + r) * 256 + k0 + sg * 8);
        }
        __syncthreads();
        bf16x8 af[2], bfr[2];
        #pragma unroll
        for (int mt = 0; mt < 2; ++mt)
            af[mt] = *reinterpret_cast<const bf16x8*>(&As[(wm * 32 + mt * 16 + l16) * LDT + quad * 8]);
        #pragma unroll
        for (int nt = 0; nt < 2; ++nt)
            bfr[nt] = *reinterpret_cast<const bf16x8*>(&Bs[(wn * 32 + nt * 16 + l16) * LDT + quad * 8]);
        #pragma unroll
        for (int mt = 0; mt < 2; ++mt)
            #pragma unroll
            for (int nt = 0; nt < 2; ++nt)
                acc[mt][nt] = __builtin_amdgcn_mfma_f32_16x16x32_bf16(af[mt], bfr[nt], acc[mt][nt], 0, 0, 0);
        __syncthreads();
    }

    #pragma unroll
    for (int mt = 0; mt < 2; ++mt) {
        #pragma unroll
        for (int nt = 0; nt < 2; ++nt) {
            int colL = bn + wn * 32 + nt * 16 + l16;
            #pragma unroll
            for (int r = 0; r < 4; ++r) {
                int row = bm + wm * 32 + mt * 16 + quad * 4 + r;
                float v = acc[mt][nt][r];
                if (g.bias) {
                    float bv = g.bias[colL];
                    if (g.rowscale) bv *= g.rowscale[row];
                    v += bv;
                }
                if (g.extra) v += g.esc * g.extra[(size_t)eidx[row] * QD + colL];
                v *= g.cscale;
                if (g.vtout)
                    g.C[(size_t)colL * 4096 + row] = __float2bfloat16(v);
                else if (g.Cf)
                    g.Cf[(size_t)row * g.ldc + g.coloff + colL] = v;
                else
                    g.C[(size_t)row * g.ldc + g.coloff + colL] = __float2bfloat16(v);
            }
        }
    }
}

// ---------------------------------------------------------------------------
// fp32 tiled composite-weight GEMM (startup): 32x32 tile, BK=16, 2x2 microtile.
// ---------------------------------------------------------------------------
struct FDesc { const float* A; int lda; const float* B; int ldb; int tb;
               const float* bias; float* C; int M, N, K; };
struct FPack { FDesc d[16]; };

__global__ __launch_bounds__(256) void fgemm2(FPack p)
{
    FDesc c = p.d[blockIdx.z];
    int bm = blockIdx.y * 32, bn = blockIdx.x * 32;
    if (bm >= c.M || bn >= c.N) return;
    __shared__ float As[16][33];
    __shared__ float Bs[16][33];
    int tid = threadIdx.x;
    int tr = tid / 16, tc = tid % 16;
    float acc[2][2] = {};

    for (int k0 = 0; k0 < c.K; k0 += 16) {
        #pragma unroll
        for (int u = 0; u < 2; ++u) {
            int i = tid * 2 + u;
            int m = i >> 4, kk = i & 15;
            int row = bm + m, kg = k0 + kk;
            As[kk][m] = (row < c.M && kg < c.K) ? c.A[(size_t)row * c.lda + kg] : 0.f;
        }
        if (c.tb) {
            #pragma unroll
            for (int u = 0; u < 2; ++u) {
                int i = tid * 2 + u;
                int n = i >> 4, kk = i & 15;
                int col = bn + n, kg = k0 + kk;
                Bs[kk][n] = (col < c.N && kg < c.K) ? c.B[(size_t)col * c.ldb + kg] : 0.f;
            }
        } else {
            #pragma unroll
            for (int u = 0; u < 2; ++u) {
                int i = tid * 2 + u;
                int kk = i >> 5, n = i & 31;
                int col = bn + n, kg = k0 + kk;
                Bs[kk][n] = (col < c.N && kg < c.K) ? c.B[(size_t)kg * c.ldb + col] : 0.f;
            }
        }
        __syncthreads();
        #pragma unroll
        for (int kk = 0; kk < 16; ++kk) {
            float a0 = As[kk][tr * 2], a1 = As[kk][tr * 2 + 1];
            float b0 = Bs[kk][tc * 2], b1 = Bs[kk][tc * 2 + 1];
            acc[0][0] = fmaf(a0, b0, acc[0][0]);
            acc[0][1] = fmaf(a0, b1, acc[0][1]);
            acc[1][0] = fmaf(a1, b0, acc[1][0]);
            acc[1][1] = fmaf(a1, b1, acc[1][1]);
        }
        __syncthreads();
    }

    #pragma unroll
    for (int i = 0; i < 2; ++i) {
        int row = bm + tr * 2 + i;
        if (row >= c.M) continue;
        #pragma unroll
        for (int j = 0; j < 2; ++j) {
            int col = bn + tc * 2 + j;
            if (col >= c.N) continue;
            float v = acc[i][j];
            if (c.bias) v += c.bias[col];
            c.C[(size_t)row * c.N + col] = v;
        }
    }
}

// ---------------------------------------------------------------------------
// Flash MHA v12: key-split across grid.z=2 (1024 blocks -> 4 blocks/CU, the
// v10 structure was grid-limited to 2 blocks/CU: 30% occupancy, 30% idle
// issue).  Same 8-wave inner body as v10b (4 q-sets, ones-MFMA row-sum);
// merge shrunk to 2 LDS stages (Osh[4] = 37.9KB -> 4 blocks/CU), partials
// atomicAdd'd to fp32 global (max-free softmax is additive; 2 adds/location
// is order-independent).  mha_norm divides and converts.
// ---------------------------------------------------------------------------
__global__ __launch_bounds__(512, 4) void mha_flash12(
    const __hip_bfloat16* __restrict__ Qm,
    const __hip_bfloat16* __restrict__ Km,
    const __hip_bfloat16* __restrict__ Vt,
    float* __restrict__ Of, float* __restrict__ Lf)
{
    const int hh = blockIdx.y;
    const int tid = threadIdx.x;
    const int w = tid >> 6, lane = tid & 63, l16 = lane & 15, quad = lane >> 4;
    const int qb = blockIdx.x * 64;

    __shared__ float Osh[4][4][64][9];   // 36,864 B
    __shared__ float Lsh[4][4][16];      //  1,024 B

    bf16x8 aq[4];
    #pragma unroll
    for (int s = 0; s < 4; ++s)
        aq[s] = *reinterpret_cast<const bf16x8*>(
            Qm + (size_t)(qb + s * 16 + l16) * 256 + hh * 32 + quad * 8);
    const __hip_bfloat16* vb0 = Vt + (size_t)(hh * 32 + l16) * 4096;
    const __hip_bfloat16* vb1 = vb0 + (size_t)16 * 4096;
    const int rowoff = (l16 >> 2) * 8 + (l16 & 3);
    const f32x4 zero = {0.f, 0.f, 0.f, 0.f};

    PU onesu;
    #pragma unroll
    for (int j = 0; j < 8; ++j) onesu.h[j] = __float2bfloat16(1.f);
    const bf16x8 onesv = onesu.v;

    f32x4 o0[4], o1[4], lac[4];
    #pragma unroll
    for (int s = 0; s < 4; ++s) { o0[s] = zero; o1[s] = zero; lac[s] = zero; }

    const int kstart = (blockIdx.z * 8 + w) * 256;
    for (int kt = 0; kt < 4; ++kt) {
        const int kbase = kstart + kt * 64;
        bf16x8 kf[4];
        #pragma unroll
        for (int c = 0; c < 2; ++c)
            #pragma unroll
            for (int st = 0; st < 2; ++st)
                kf[c * 2 + st] = *reinterpret_cast<const bf16x8*>(
                    Km + (size_t)(kbase + c * 32 + st * 4 + rowoff) * 256 + hh * 32 + quad * 8);
        bf16x8 v00 = *reinterpret_cast<const bf16x8*>(vb0 + kbase + quad * 8);
        bf16x8 v01 = *reinterpret_cast<const bf16x8*>(vb1 + kbase + quad * 8);
        bf16x8 v10 = *reinterpret_cast<const bf16x8*>(vb0 + kbase + 32 + quad * 8);
        bf16x8 v11 = *reinterpret_cast<const bf16x8*>(vb1 + kbase + 32 + quad * 8);

        #pragma unroll
        for (int s = 0; s < 4; ++s) {
            f32x4 sv[4];
            __builtin_amdgcn_s_setprio(1);
            #pragma unroll
            for (int i = 0; i < 4; ++i)
                sv[i] = __builtin_amdgcn_mfma_f32_16x16x32_bf16(kf[i], aq[s], zero, 0, 0, 0);
            __builtin_amdgcn_s_setprio(0);
            PU p0, p1;
            #pragma unroll
            for (int i = 0; i < 4; ++i) {
                float e0 = exp2f(sv[i][0]), e1 = exp2f(sv[i][1]);
                float e2 = exp2f(sv[i][2]), e3 = exp2f(sv[i][3]);
                PU& pp = (i < 2) ? p0 : p1;
                pp.b2[(i & 1) * 2 + 0] = __float22bfloat162_rn(make_float2(e0, e1));
                pp.b2[(i & 1) * 2 + 1] = __float22bfloat162_rn(make_float2(e2, e3));
            }
            __builtin_amdgcn_s_setprio(1);
            o0[s]  = __builtin_amdgcn_mfma_f32_16x16x32_bf16(v00,   p0.v, o0[s],  0, 0, 0);
            o1[s]  = __builtin_amdgcn_mfma_f32_16x16x32_bf16(v01,   p0.v, o1[s],  0, 0, 0);
            lac[s] = __builtin_amdgcn_mfma_f32_16x16x32_bf16(onesv, p0.v, lac[s], 0, 0, 0);
            o0[s]  = __builtin_amdgcn_mfma_f32_16x16x32_bf16(v10,   p1.v, o0[s],  0, 0, 0);
            o1[s]  = __builtin_amdgcn_mfma_f32_16x16x32_bf16(v11,   p1.v, o1[s],  0, 0, 0);
            lac[s] = __builtin_amdgcn_mfma_f32_16x16x32_bf16(onesv, p1.v, lac[s], 0, 0, 0);
            __builtin_amdgcn_s_setprio(0);
        }
    }

    float lsum[4];
    #pragma unroll
    for (int s = 0; s < 4; ++s) lsum[s] = lac[s][0];

    // ---- stage A: 8 -> 4 (waves 4-7 write slot w-4, waves 0-3 accumulate) ----
    if (w >= 4) {
        #pragma unroll
        for (int s = 0; s < 4; ++s) {
            #pragma unroll
            for (int r = 0; r < 4; ++r) {
                Osh[w - 4][s][lane][r]     = o0[s][r];
                Osh[w - 4][s][lane][4 + r] = o1[s][r];
            }
            if (quad == 0) Lsh[w - 4][s][l16] = lsum[s];
        }
    }
    __syncthreads();
    if (w < 4) {
        #pragma unroll
        for (int s = 0; s < 4; ++s) {
            #pragma unroll
            for (int r = 0; r < 4; ++r) {
                o0[s][r] += Osh[w][s][lane][r];
                o1[s][r] += Osh[w][s][lane][4 + r];
            }
            lsum[s] += Lsh[w][s][l16];
        }
    }
    __syncthreads();
    // ---- stage B: distributed exchange — wave j finalizes set j ----
    if (w < 4) {
        #pragma unroll
        for (int s = 0; s < 4; ++s) {
            if (s == w) continue;
            #pragma unroll
            for (int r = 0; r < 4; ++r) {
                Osh[w][s][lane][r]     = o0[s][r];
                Osh[w][s][lane][4 + r] = o1[s][r];
            }
            if (quad == 0) Lsh[w][s][l16] = lsum[s];
        }
    }
    __syncthreads();
    if (w < 4) {
        const int s = w;
        f32x4 a0 = o0[s], a1 = o1[s];
        float ll = lsum[s];
        #pragma unroll
        for (int i = 0; i < 4; ++i) {
            if (i == s) continue;
            #pragma unroll
            for (int r = 0; r < 4; ++r) {
                a0[r] += Osh[i][s][lane][r];
                a1[r] += Osh[i][s][lane][4 + r];
            }
            ll += Lsh[i][s][l16];
        }
        float* dst = Of + (size_t)(qb + s * 16 + l16) * 256 + hh * 32;
        #pragma unroll
        for (int r = 0; r < 4; ++r) {
            atomicAdd(&dst[quad * 4 + r],      a0[r]);
            atomicAdd(&dst[16 + quad * 4 + r], a1[r]);
        }
        if (quad == 0)
            atomicAdd(&Lf[hh * N_NODES + qb + s * 16 + l16], ll);
    }
}

// out[row][t] = Of[row][t] / Lf[head(t)][row], bf16
__global__ __launch_bounds__(256) void mha_norm(
    const float* __restrict__ Of, const float* __restrict__ Lf,
    __hip_bfloat16* __restrict__ Out)
{
    int row = blockIdx.x, t = threadIdx.x;
    int head = t >> 5;
    float v = Of[(size_t)row * 256 + t] / Lf[head * N_NODES + row];
    Out[(size_t)row * 256 + t] = __float2bfloat16(v);
}

// build mask bitfield + per-target degree count in one pass
__global__ __launch_bounds__(256) void build_mask(const int* __restrict__ src,
                                                  const int* __restrict__ tgt,
                                                  unsigned* __restrict__ mb,
                                                  int* __restrict__ cnt)
{
    int e = blockIdx.x * 256 + threadIdx.x;
    if (e >= E_EDGES) return;
    int t = tgt[e];
    atomicOr(mb + (size_t)src[e] * (N_NODES / 32) + (t >> 5), 1u << (t & 31));
    atomicAdd(&cnt[t], 1);
}

__global__ __launch_bounds__(1024) void csr_scan(const int* __restrict__ cnt, int* __restrict__ off,
                                                 int* __restrict__ cursor, float* __restrict__ degf)
{
    __shared__ int sh[1024];
    int t = threadIdx.x;
    int base = t * 4;
    int c0 = cnt[base], c1 = cnt[base + 1], c2 = cnt[base + 2], c3 = cnt[base + 3];
    int sum = c0 + c1 + c2 + c3;
    sh[t] = sum; __syncthreads();
    for (int d = 1; d < 1024; d <<= 1) {
        int v = (t >= d) ? sh[t - d] : 0;
        __syncthreads();
        sh[t] += v;
        __syncthreads();
    }
    int excl = sh[t] - sum;
    int o0 = excl, o1 = excl + c0, o2 = o1 + c1, o3 = o2 + c2;
    off[base] = o0; off[base + 1] = o1; off[base + 2] = o2; off[base + 3] = o3;
    cursor[base] = o0; cursor[base + 1] = o1; cursor[base + 2] = o2; cursor[base + 3] = o3;
    degf[base] = (float)c0; degf[base + 1] = (float)c1;
    degf[base + 2] = (float)c2; degf[base + 3] = (float)c3;
    if (t == 1023) off[4096] = sh[t];
}

__global__ __launch_bounds__(256) void csr_fill(const int* __restrict__ src, const int* __restrict__ tgt,
                                                int* __restrict__ cursor,
                                                int* __restrict__ srcp, int* __restrict__ tgtp)
{
    int e = blockIdx.x * 256 + threadIdx.x;
    if (e >= E_EDGES) return;
    int t = tgt[e];
    int pos = atomicAdd(&cursor[t], 1);
    srcp[pos] = src[e];
    tgtp[pos] = t;
}

__global__ __launch_bounds__(256) void seg_sum(const int* __restrict__ off,
                                               const __hip_bfloat16* __restrict__ M2,
                                               __hip_bfloat16* __restrict__ A3)
{
    int n = blockIdx.x, t = threadIdx.x;
    int b0 = off[n], b1 = off[n + 1];
    float s = 0.f;
    for (int i = b0; i < b1; ++i)
        s += __bfloat162float(M2[(size_t)i * 256 + t]);
    A3[(size_t)n * 256 + t] = __float2bfloat16(s);
}

// Sparse graph-masked attention over bf16 Q,K,V. Writes out (=).
__global__ __launch_bounds__(256) void sparse_attn(
    const __hip_bfloat16* __restrict__ Q, const __hip_bfloat16* __restrict__ K,
    const __hip_bfloat16* __restrict__ V, int vld,
    const unsigned* __restrict__ maskb, float* __restrict__ outb)
{
    int i = blockIdx.x, t = threadIdx.x;
    __shared__ float qsh[256];
    __shared__ int   nb[1024];
    __shared__ float sc[1024];
    __shared__ int   cnt;
    __shared__ float red[4];
    __shared__ float smax, ssum;
    if (t == 0) cnt = 0;
    qsh[t] = __bfloat162float(Q[(size_t)i * 256 + t]);
    __syncthreads();
    if (t < 128) {
        unsigned wv = maskb[(size_t)i * 128 + t];
        while (wv) {
            int b = __ffs(wv) - 1; wv &= wv - 1;
            int p = atomicAdd(&cnt, 1);
            nb[p] = t * 32 + b;
        }
    }
    __syncthreads();
    int deg = cnt;
    int wid = t >> 6, lane = t & 63;
    if (deg > 0) {
        for (int n = wid; n < deg; n += 4) {
            union { uint2 u; __hip_bfloat16 h[4]; } kv;
            kv.u = *reinterpret_cast<const uint2*>(K + (size_t)nb[n] * 256 + lane * 4);
            float s = qsh[lane*4+0] * __bfloat162float(kv.h[0]) + qsh[lane*4+1] * __bfloat162float(kv.h[1])
                    + qsh[lane*4+2] * __bfloat162float(kv.h[2]) + qsh[lane*4+3] * __bfloat162float(kv.h[3]);
            #pragma unroll
            for (int off = 32; off; off >>= 1) s += __shfl_xor(s, off);
            if (lane == 0) sc[n] = s * 0.0625f;
        }
        __syncthreads();
        float m = -3.4e38f;
        for (int n = t; n < deg; n += 256) m = fmaxf(m, sc[n]);
        #pragma unroll
        for (int off = 32; off; off >>= 1) m = fmaxf(m, __shfl_xor(m, off));
        if (lane == 0) red[wid] = m;
        __syncthreads();
        if (t == 0) smax = fmaxf(fmaxf(red[0], red[1]), fmaxf(red[2], red[3]));
        __syncthreads();
        float ls = 0.f;
        for (int n = t; n < deg; n += 256) { float e = __expf(sc[n] - smax); sc[n] = e; ls += e; }
        #pragma unroll
        for (int off = 32; off; off >>= 1) ls += __shfl_xor(ls, off);
        if (lane == 0) red[wid] = ls;
        __syncthreads();
        if (t == 0) ssum = red[0] + red[1] + red[2] + red[3];
        __syncthreads();
        float inv = 1.f / ssum;
        float o = 0.f;
        for (int n = 0; n < deg; ++n)
            o += sc[n] * __bfloat162float(V[(size_t)nb[n] * vld + t]);
        outb[(size_t)i * 256 + t] = o * inv;
    } else {
        float o = 0.f;
        for (int j = 0; j < N_NODES; ++j) o += __bfloat162float(V[(size_t)j * vld + t]);
        outb[(size_t)i * 256 + t] = o * (1.f / N_NODES);
    }
}

// h = LN(h + a1 + a2 + a3)
__global__ __launch_bounds__(256) void ln_kernel(float* __restrict__ h, __hip_bfloat16* __restrict__ h16,
                                                 const float* __restrict__ a1,
                                                 const float* __restrict__ a2,
                                                 const float* __restrict__ a3,
                                                 const float* __restrict__ g, const float* __restrict__ b)
{
    int row = blockIdx.x, t = threadIdx.x;
    __shared__ float red[256];
    size_t off = ((size_t)row << 8) + t;
    float v = h[off] + a1[off] + a2[off] + a3[off];
    red[t] = v; __syncthreads();
    for (int s = 128; s > 0; s >>= 1) { if (t < s) red[t] += red[t + s]; __syncthreads(); }
    float mu = red[0] * (1.f / 256.f); __syncthreads();
    float d = v - mu;
    red[t] = d * d; __syncthreads();
    for (int s = 128; s > 0; s >>= 1) { if (t < s) red[t] += red[t + s]; __syncthreads(); }
    float var = red[0] * (1.f / 256.f);
    float r = d * rsqrtf(var + 1e-5f) * g[t] + b[t];
    h[off] = r;
    h16[off] = __float2bfloat16(r);
}

__global__ __launch_bounds__(256) void colpool(const float* __restrict__ h, float* __restrict__ p)
{
    int c = blockIdx.x, t = threadIdx.x;
    __shared__ float rs[256], rm[256];
    float s = 0.f, m = -3.4e38f;
    for (int row = t; row < N_NODES; row += 256) {
        float v = h[((size_t)row << 8) + c];
        s += v; m = fmaxf(m, v);
    }
    rs[t] = s; rm[t] = m; __syncthreads();
    for (int st = 128; st > 0; st >>= 1) {
        if (t < st) { rs[t] += rs[t + st]; rm[t] = fmaxf(rm[t], rm[t + st]); }
        __syncthreads();
    }
    if (t == 0) { p[c] = rs[0] * (1.f / N_NODES); p[256 + c] = rm[0]; }
}

__global__ __launch_bounds__(256) void classifier(const float* __restrict__ pooled,
                                                  const float* __restrict__ Wc1, const float* __restrict__ bc1,
                                                  const float* __restrict__ Wc2, const float* __restrict__ bc2,
                                                  float* __restrict__ out)
{
    __shared__ float p[512];
    __shared__ float z[256];
    int t = threadIdx.x;
    p[t] = pooled[t]; p[256 + t] = pooled[256 + t];
    __syncthreads();
    float s = bc1[t];
    for (int k = 0; k < 512; ++k) s = fmaf(p[k], Wc1[k * 256 + t], s);
    z[t] = fmaxf(s, 0.f);
    __syncthreads();
    if (t < OUT_F) {
        float o = bc2[t];
        for (int j = 0; j < 256; ++j) o = fmaf(z[j], Wc2[j * OUT_F + t], o);
        out[t] = o;
    }
}

// ---- bf16 conversion ----
struct CDesc { const float* s; __hip_bfloat16* d; int total; };
struct CPack { CDesc d[2]; };
__global__ __launch_bounds__(256) void convert_copy(CPack p)
{
    CDesc c = p.d[blockIdx.y];
    for (int i = blockIdx.x * 256 + threadIdx.x; i < c.total; i += gridDim.x * 256)
        c.d[i] = __float2bfloat16(c.s[i]);
}
// LDS-tiled transpose-convert: d[n*K+k] = bf16(s[k*sld+n]); coalesced both sides
struct TDesc { const float* s; __hip_bfloat16* d; int K, N, sld; };
struct TPack { TDesc d[23]; };
__global__ __launch_bounds__(256) void convert_t32(TPack p)
{
    TDesc c = p.d[blockIdx.z];
    int k0 = blockIdx.x * 32, n0 = blockIdx.y * 32;
    if (k0 >= c.K || n0 >= c.N) return;
    __shared__ float t[32][33];
    int tr = threadIdx.x >> 5, tc = threadIdx.x & 31;
    #pragma unroll
    for (int rr = 0; rr < 32; rr += 8)
        t[tc][tr + rr] = c.s[(size_t)(k0 + tr + rr) * c.sld + n0 + tc];
    __syncthreads();
    #pragma unroll
    for (int rr = 0; rr < 32; rr += 8)
        c.d[(size_t)(n0 + tr + rr) * c.K + k0 + tc] = __float2bfloat16(t[tr + rr][tc]);
}

extern "C" void kernel_launch(void* const* d_in, const int* in_sizes, int n_in,
                              void* d_out, int out_size, void* d_ws, size_t ws_size,
                              hipStream_t stream)
{
    const float* x    = (const float*)d_in[0];
    const int*   ei   = (const int*)d_in[1];
    const int*   ct   = (const int*)d_in[2];
    const float* Wi   = (const float*)d_in[3];
    const float* bi   = (const float*)d_in[4];
    const float* Wq   = (const float*)d_in[5];
    const float* bq   = (const float*)d_in[6];
    const float* Wk   = (const float*)d_in[7];
    const float* bk   = (const float*)d_in[8];
    const float* Wv   = (const float*)d_in[9];
    const float* bv   = (const float*)d_in[10];
    const float* Bc   = (const float*)d_in[11];
    const float* cemb = (const float*)d_in[12];
    const float* Win  = (const float*)d_in[13];
    const float* binp = (const float*)d_in[14];
    const float* Wo   = (const float*)d_in[15];
    const float* bo   = (const float*)d_in[16];
    const float* Wm1  = (const float*)d_in[17];
    const float* bm1  = (const float*)d_in[18];
    const float* Wm2  = (const float*)d_in[19];
    const float* bm2  = (const float*)d_in[20];
    const float* Wm3  = (const float*)d_in[21];
    const float* bm3  = (const float*)d_in[22];
    const float* lng  = (const float*)d_in[23];
    const float* lnb  = (const float*)d_in[24];
    const float* Wc1  = (const float*)d_in[25];
    const float* bc1  = (const float*)d_in[26];
    const float* Wc2  = (const float*)d_in[27];
    const float* bc2  = (const float*)d_in[28];

    const int* src = ei;
    const int* tgt = ei + E_EDGES;

    // ---- workspace carve-up ----
    char* wp = (char*)d_ws;
    auto alloc = [&](size_t bytes) { char* r = wp; wp += (bytes + 255) & ~(size_t)255; return r; };
    const size_t NH = (size_t)N_NODES * 256;
    float* h      = (float*)alloc(NH * 4);
    float* a1     = (float*)alloc(NH * 4);
    float* a2     = (float*)alloc(NH * 4);
    float* a3     = (float*)alloc(NH * 4);
    float* pooled = (float*)alloc(512 * 4);
    float* degf   = (float*)alloc(N_NODES * 4);
    float* Of     = (float*)alloc(NH * 4);               // mha partial O (fp32)
    float* Lf     = (float*)alloc((size_t)NHEAD * N_NODES * 4);  // mha partial l
    __hip_bfloat16* x16 = (__hip_bfloat16*)alloc((size_t)N_NODES * 512 * 2);
    __hip_bfloat16* h16 = (__hip_bfloat16*)alloc(NH * 2);
    __hip_bfloat16* Qb  = (__hip_bfloat16*)alloc(NH * 2);
    __hip_bfloat16* Kb  = (__hip_bfloat16*)alloc(NH * 2);
    __hip_bfloat16* Vb  = (__hip_bfloat16*)alloc(NH * 2);
    __hip_bfloat16* Tq  = (__hip_bfloat16*)alloc(NH * 2);
    __hip_bfloat16* Tk  = (__hip_bfloat16*)alloc(NH * 2);
    __hip_bfloat16* Vt  = (__hip_bfloat16*)alloc(NH * 2);
    __hip_bfloat16* Z12 = (__hip_bfloat16*)alloc((size_t)N_NODES * 512 * 2);
    __hip_bfloat16* M216= (__hip_bfloat16*)alloc((size_t)E_EDGES * 256 * 2);
    __hip_bfloat16* A3  = (__hip_bfloat16*)alloc(NH * 2);
    __hip_bfloat16* Wi_t= (__hip_bfloat16*)alloc((size_t)256 * 512 * 2);
    // fp32 composite weights / biases / ce-tables, per layer
    float *Wqc_f[2], *Wkc_f[2], *Wqm_f[2], *Wkm_f[2], *Wvm_f[2];
    float *bqc[2], *bkc[2], *bqm[2], *bkm[2], *bvm[2], *ceq2[2], *cek2[2];
    for (int l = 0; l < 2; ++l) {
        Wqc_f[l] = (float*)alloc(65536 * 4); Wkc_f[l] = (float*)alloc(65536 * 4);
        Wqm_f[l] = (float*)alloc(65536 * 4); Wkm_f[l] = (float*)alloc(65536 * 4);
        Wvm_f[l] = (float*)alloc(65536 * 4);
        bqc[l] = (float*)alloc(256 * 4); bkc[l] = (float*)alloc(256 * 4);
        bqm[l] = (float*)alloc(256 * 4); bkm[l] = (float*)alloc(256 * 4);
        bvm[l] = (float*)alloc(256 * 4);
        ceq2[l] = (float*)alloc(CT_N * 256 * 4); cek2[l] = (float*)alloc(CT_N * 256 * 4);
    }
    // bf16 [N][K] weights: per layer: Wqc,Wkc,Wqm,Wkm,Wvm,Wv,Wo,Wm1a,Wm1b,Wm2,Wm3
    __hip_bfloat16* WB[2][11];
    for (int l = 0; l < 2; ++l)
        for (int m = 0; m < 11; ++m)
            WB[l][m] = (__hip_bfloat16*)alloc(65536 * 2);
    unsigned* maskb = (unsigned*)alloc((size_t)N_NODES * 128 * 4);
    int* cnt    = (int*)alloc(N_NODES * 4);
    int* cursor = (int*)alloc(N_NODES * 4);
    int* off    = (int*)alloc((N_NODES + 1) * 4);
    int* srcp   = (int*)alloc(E_EDGES * 4);
    int* tgtp   = (int*)alloc(E_EDGES * 4);

    // ---- startup: x conversion ----
    CPack cp; cp.d[0] = {x, x16, N_NODES * 512};
    convert_copy<<<dim3(256, 1), 256, 0, stream>>>(cp);

    // ---- composite fp32 weights (tiled fgemm2, 2 dependent waves) ----
    FPack f1; int n1 = 0;
    FPack f2; int n2 = 0;
    for (int l = 0; l < 2; ++l) {
        const float* Wq_l  = Wq + (size_t)l * 65536;
        const float* Wk_l  = Wk + (size_t)l * 65536;
        const float* Wv_l  = Wv + (size_t)l * 65536;
        const float* Bc_l  = Bc + (size_t)l * 65536;
        const float* Win_l = Win + (size_t)l * 256 * 768;
        const float* ce_l  = cemb + (size_t)l * CT_N * QD;
        const float* bq_l  = bq + l * 256;
        const float* bk_l  = bk + l * 256;
        const float* bv_l  = bv + l * 256;
        const float* bin_l = binp + l * 768;
        f1.d[n1++] = {Wq_l, 256, Bc_l, 256, 0, nullptr, Wqc_f[l], 256, 256, 256};
        f1.d[n1++] = {Wk_l, 256, Bc_l, 256, 1, nullptr, Wkc_f[l], 256, 256, 256};
        f1.d[n1++] = {bq_l, 256, Bc_l, 256, 0, nullptr, bqc[l], 1, 256, 256};
        f1.d[n1++] = {bk_l, 256, Bc_l, 256, 1, nullptr, bkc[l], 1, 256, 256};
        f2.d[n2++] = {Wqc_f[l], 256, Win_l,       768, 0, nullptr, Wqm_f[l], 256, 256, 256};
        f2.d[n2++] = {Wkc_f[l], 256, Win_l + 256, 768, 0, nullptr, Wkm_f[l], 256, 256, 256};
        f2.d[n2++] = {Wv_l,     256, Win_l + 512, 768, 0, nullptr, Wvm_f[l], 256, 256, 256};
        f2.d[n2++] = {ce_l,     256, Win_l,       768, 0, nullptr, ceq2[l], CT_N, 256, 256};
        f2.d[n2++] = {ce_l,     256, Win_l + 256, 768, 0, nullptr, cek2[l], CT_N, 256, 256};
        f2.d[n2++] = {bqc[l],   256, Win_l,       768, 0, bin_l,       bqm[l], 1, 256, 256};
        f2.d[n2++] = {bkc[l],   256, Win_l + 256, 768, 0, bin_l + 256, bkm[l], 1, 256, 256};
        f2.d[n2++] = {bv_l,     256, Win_l + 512, 768, 0, bin_l + 512, bvm[l], 1, 256, 256};
    }
    fgemm2<<<dim3(8, 8, n1), 256, 0, stream>>>(f1);
    fgemm2<<<dim3(8, 8, n2), 256, 0, stream>>>(f2);

    // ---- transpose-convert all [K][N] fp32 weights to bf16 [N][K] ----
    TPack tp; int ndt = 0;
    auto addT = [&](const float* s, __hip_bfloat16* d, int K, int N, int sld) { tp.d[ndt++] = {s, d, K, N, sld}; };
    addT(Wi, Wi_t, 512, 256, 256);
    for (int l = 0; l < 2; ++l) {
        const float* Wv_l  = Wv + (size_t)l * 65536;
        const float* Wo_l  = Wo + (size_t)l * 65536;
        const float* Wm1_l = Wm1 + (size_t)l * (2 * H_F + QD) * QD;  // layer stride 768*256!
        const float* Wm2_l = Wm2 + (size_t)l * 65536;
        const float* Wm3_l = Wm3 + (size_t)l * 65536;
        addT(Wqc_f[l], WB[l][0], 256, 256, 256);
        addT(Wkc_f[l], WB[l][1], 256, 256, 256);
        addT(Wqm_f[l], WB[l][2], 256, 256, 256);
        addT(Wkm_f[l], WB[l][3], 256, 256, 256);
        addT(Wvm_f[l], WB[l][4], 256, 256, 256);
        addT(Wv_l,     WB[l][5], 256, 256, 256);
        addT(Wo_l,     WB[l][6], 256, 256, 256);
        addT(Wm1_l,             WB[l][7], 256, 256, 256);
        addT(Wm1_l + 256 * 256, WB[l][8], 256, 256, 256);
        addT(Wm2_l,    WB[l][9],  256, 256, 256);
        addT(Wm3_l,    WB[l][10], 256, 256, 256);
    }
    convert_t32<<<dim3(16, 8, ndt), 256, 0, stream>>>(tp);

    hipMemsetAsync(maskb, 0, (size_t)N_NODES * 128 * 4, stream);
    hipMemsetAsync(cnt, 0, N_NODES * 4, stream);
    build_mask<<<E_EDGES / 256, 256, 0, stream>>>(src, tgt, maskb, cnt);
    csr_scan<<<1, 1024, 0, stream>>>(cnt, off, cursor, degf);
    csr_fill<<<E_EDGES / 256, 256, 0, stream>>>(src, tgt, cursor, srcp, tgtp);

    // h = relu(x @ Wi + bi)
    gemm_mfma<64, 64, false><<<dim3(4, 64), 256, 0, stream>>>(
        x16, 512, Wi_t, 512, h, h16, 256, 512,
        bi, nullptr, nullptr, nullptr, nullptr, FLAG_RELU | FLAG_WF32 | FLAG_WB16);

    const float QSCALE = 0.25507693f;   // log2(e)/sqrt(32)

    for (int l = 0; l < L_LAYERS; ++l) {
        const float* ce_l  = cemb + (size_t)l * CT_N * QD;
        const float* bo_l  = bo + l * QD;
        const float* bm1_l = bm1 + l * QD;
        const float* bm2_l = bm2 + l * QD;
        const float* bm3_l = bm3 + l * H_F;
        const float* lng_l = lng + l * H_F;
        const float* lnb_l = lnb + l * H_F;
        const float* bv_l  = bv + l * 256;

        // ---- one z=8 projection launch from h ----
        {
            GPack gp;
            gp.s[0] = {h16, 256, WB[l][0], bqc[l], nullptr, ce_l,    0.1f, 1.0f,   Qb,  nullptr, 0, 256, 0};
            gp.s[1] = {h16, 256, WB[l][1], bkc[l], nullptr, ce_l,    0.1f, 1.0f,   Kb,  nullptr, 0, 256, 0};
            gp.s[2] = {h16, 256, WB[l][5], bv_l,   nullptr, nullptr, 0.f,  1.0f,   Vb,  nullptr, 0, 256, 0};
            gp.s[3] = {h16, 256, WB[l][2], bqm[l], nullptr, ceq2[l], 0.1f, QSCALE, Tq,  nullptr, 0, 256, 0};
            gp.s[4] = {h16, 256, WB[l][3], bkm[l], nullptr, cek2[l], 0.1f, 1.0f,   Tk,  nullptr, 0, 256, 0};
            gp.s[5] = {h16, 256, WB[l][4], bvm[l], nullptr, nullptr, 0.f,  1.0f,   Vt,  nullptr, 1, 256, 0};
            gp.s[6] = {h16, 256, WB[l][7], nullptr, nullptr, nullptr, 0.f, 1.0f,   Z12, nullptr, 0, 512, 0};
            gp.s[7] = {h16, 256, WB[l][8], nullptr, nullptr, nullptr, 0.f, 1.0f,   Z12, nullptr, 0, 512, 256};
            gemm_bz<<<dim3(4, 64, 8), 256, 0, stream>>>(gp, ct);
        }

        // zero mha partial buffers (overlaps nothing; ~1 us)
        hipMemsetAsync(Of, 0, NH * 4, stream);
        hipMemsetAsync(Lf, 0, (size_t)NHEAD * N_NODES * 4, stream);

        // sparse graph-masked attention -> a1
        sparse_attn<<<N_NODES, 256, 0, stream>>>(Qb, Kb, Vb, 256, maskb, a1);

        // flash MHA v12 (key-split z=2, 4 blocks/CU) -> Of/Lf, then normalize -> Qb
        mha_flash12<<<dim3(64, NHEAD, 2), 512, 0, stream>>>(Tq, Tk, Vt, Of, Lf);
        mha_norm<<<N_NODES, 256, 0, stream>>>(Of, Lf, Qb);

        // edge MLP: gather-once full-K edge GEMM -> M216, seg-sum -> A3
        edge_gemm<<<E_EDGES / 64, 512, 0, stream>>>(
            Z12, WB[l][9], M216, tgtp, srcp, bm1_l, bm2_l);
        seg_sum<<<N_NODES, 256, 0, stream>>>(off, M216, A3);

        // batched fp32 outputs: a2 = heads@Wo + bo ; a3 = A3@Wm3 + deg*bm3
        {
            GPack gp;
            gp.s[0] = {Qb, 256, WB[l][6],  bo_l,  nullptr, nullptr, 0.f, 1.0f, nullptr, a2, 0, 256, 0};
            gp.s[1] = {A3, 256, WB[l][10], bm3_l, degf,    nullptr, 0.f, 1.0f, nullptr, a3, 0, 256, 0};
            gemm_bz<<<dim3(4, 64, 2), 256, 0, stream>>>(gp, ct);
        }

        // h = LN(h + a1 + a2 + a3)
        ln_kernel<<<N_NODES, 256, 0, stream>>>(h, h16, a1, a2, a3, lng_l, lnb_l);
    }

    colpool<<<H_F, 256, 0, stream>>>(h, pooled);
    classifier<<<1, 256, 0, stream>>>(pooled, Wc1, bc1, Wc2, bc2, (float*)d_out);
}

// Round 7
// 517.099 us; speedup vs baseline: 1.0970x; 1.0970x over previous
//
#include <hip/hip_runtime.h>
#include <hip/hip_bf16.h>

#define N_NODES 4096
#define E_EDGES 65536
#define IN_F    512
#define H_F     256
#define QD      256
#define NHEAD   8
#define HD      32
#define OUT_F   10
#define L_LAYERS 2
#define CT_N    50

enum { FLAG_RELU = 1, FLAG_ACCUM = 2, FLAG_WF32 = 4, FLAG_WB16 = 8 };

typedef __attribute__((ext_vector_type(8))) __bf16 bf16x8;
typedef __attribute__((ext_vector_type(4))) float f32x4;

union PU { bf16x8 v; __hip_bfloat16 h[8]; __hip_bfloat162 b2[4]; };

// ---------------------------------------------------------------------------
// bf16 MFMA GEMM.  A: bf16 [M][K] row-major (lda).  B: bf16 [N][K] (B^T layout).
// ---------------------------------------------------------------------------
template<int BM, int BN, bool EDGE>
__global__ __launch_bounds__(256) void gemm_mfma(
    const __hip_bfloat16* __restrict__ A, int lda,
    const __hip_bfloat16* __restrict__ B, int ldb,
    float* __restrict__ Cf, __hip_bfloat16* __restrict__ Cb, int ldc,
    int K,
    const float* __restrict__ bias, const float* __restrict__ rowscale,
    const int* __restrict__ tgtp, const int* __restrict__ srcp,
    const float* __restrict__ kbias,
    int flags)
{
    constexpr int WM = BM / 2, WN = BN / 2, MT = WM / 16, NT = WN / 16;
    constexpr int LDT = 40;   // 80B row stride -> max 2-way bank alias (free, m136)
    __shared__ alignas(16) __hip_bfloat16 As[BM * LDT];
    __shared__ alignas(16) __hip_bfloat16 Bs[BN * LDT];

    const int tid = threadIdx.x;
    const int w = tid >> 6, lane = tid & 63, l16 = lane & 15, quad = lane >> 4;
    const int wm = w >> 1, wn = w & 1;
    const int bm = blockIdx.y * BM, bn = blockIdx.x * BN;

    f32x4 acc[MT][NT];
    #pragma unroll
    for (int i = 0; i < MT; ++i)
        #pragma unroll
        for (int j = 0; j < NT; ++j)
            #pragma unroll
            for (int r = 0; r < 4; ++r) acc[i][j][r] = 0.f;

    for (int k0 = 0; k0 < K; k0 += 32) {
        #pragma unroll
        for (int f = tid; f < BM * 4; f += 256) {
            int r = f >> 2, sg = f & 3;
            if (EDGE) {
                int i = bm + r;
                int tg = tgtp[i], sr = srcp[i];
                PU z1, z2, o;
                z1.v = *reinterpret_cast<const bf16x8*>(A + (size_t)tg * 512 + k0 + sg * 8);
                z2.v = *reinterpret_cast<const bf16x8*>(A + (size_t)sr * 512 + 256 + k0 + sg * 8);
                float4 b0 = *reinterpret_cast<const float4*>(kbias + k0 + sg * 8);
                float4 b1 = *reinterpret_cast<const float4*>(kbias + k0 + sg * 8 + 4);
                float bb[8] = {b0.x, b0.y, b0.z, b0.w, b1.x, b1.y, b1.z, b1.w};
                #pragma unroll
                for (int j = 0; j < 8; ++j) {
                    float v = __bfloat162float(z1.h[j]) + __bfloat162float(z2.h[j]) + bb[j];
                    o.h[j] = __float2bfloat16(fmaxf(v, 0.f));
                }
                *reinterpret_cast<bf16x8*>(&As[r * LDT + sg * 8]) = o.v;
            } else {
                *reinterpret_cast<uint4*>(&As[r * LDT + sg * 8]) =
                    *reinterpret_cast<const uint4*>(A + (size_t)(bm + r) * lda + k0 + sg * 8);
            }
        }
        #pragma unroll
        for (int f = tid; f < BN * 4; f += 256) {
            int r = f >> 2, sg = f & 3;
            *reinterpret_cast<uint4*>(&Bs[r * LDT + sg * 8]) =
                *reinterpret_cast<const uint4*>(B + (size_t)(bn + r) * ldb + k0 + sg * 8);
        }
        __syncthreads();
        bf16x8 af[MT], bfr[NT];
        #pragma unroll
        for (int mt = 0; mt < MT; ++mt)
            af[mt] = *reinterpret_cast<const bf16x8*>(&As[(wm * WM + mt * 16 + l16) * LDT + quad * 8]);
        #pragma unroll
        for (int nt = 0; nt < NT; ++nt)
            bfr[nt] = *reinterpret_cast<const bf16x8*>(&Bs[(wn * WN + nt * 16 + l16) * LDT + quad * 8]);
        #pragma unroll
        for (int mt = 0; mt < MT; ++mt)
            #pragma unroll
            for (int nt = 0; nt < NT; ++nt)
                acc[mt][nt] = __builtin_amdgcn_mfma_f32_16x16x32_bf16(af[mt], bfr[nt], acc[mt][nt], 0, 0, 0);
        __syncthreads();
    }

    #pragma unroll
    for (int mt = 0; mt < MT; ++mt) {
        #pragma unroll
        for (int nt = 0; nt < NT; ++nt) {
            int col = bn + wn * WN + nt * 16 + l16;
            #pragma unroll
            for (int r = 0; r < 4; ++r) {
                int row = bm + wm * WM + mt * 16 + quad * 4 + r;
                float v = acc[mt][nt][r];
                if (bias) {
                    float bv = bias[col];
                    if (rowscale) bv *= rowscale[row];
                    v += bv;
                }
                if (flags & FLAG_RELU) v = fmaxf(v, 0.f);
                size_t off = (size_t)row * ldc + col;
                if (flags & FLAG_ACCUM)     Cf[off] += v;
                else if (flags & FLAG_WF32) Cf[off] = v;
                if (flags & FLAG_WB16)      Cb[off] = __float2bfloat16(v);
            }
        }
    }
}

// ---------------------------------------------------------------------------
// Edge-MLP GEMM v2: M2 = relu(relu(Z[tgt][:256]+Z[src][256:]+bm1) @ Wm2 + bm2)
// Full-K gather-once into LDS + B fragments read DIRECTLY from L2 (Wm2 is
// 128KB, L2-resident, shared by all 1024 blocks) -> the K-loop has ZERO
// barriers (the 2-barrier-per-K-step Bs staging was the structural stall,
// m97-lesson).  One barrier total.  LDS 54 -> 33.8 KB.
// ---------------------------------------------------------------------------
__global__ __launch_bounds__(512, 4) void edge_gemm(
    const __hip_bfloat16* __restrict__ Z,   // [N][512] bf16 (Z12)
    const __hip_bfloat16* __restrict__ B,   // Wm2^T [256][256] bf16
    __hip_bfloat16* __restrict__ C,         // M216 [E][256] bf16
    const int* __restrict__ tgtp, const int* __restrict__ srcp,
    const float* __restrict__ kbias,        // bm1 [256]
    const float* __restrict__ bias)         // bm2 [256]
{
    constexpr int LDA = 264;   // 256 + 8 pad
    __shared__ alignas(16) __hip_bfloat16 As[64 * LDA];    // 33,792 B

    const int tid = threadIdx.x;
    const int w = tid >> 6, lane = tid & 63, l16 = lane & 15, quad = lane >> 4;
    // XCD-aware swizzle: nwg=1024, divisible by 8 -> bijective
    const int bid = blockIdx.x;
    const int bm = ((bid & 7) * 128 + (bid >> 3)) * 64;

    // ---- phase 1: gather full-K M1 rows into registers ----
    bf16x8 zt[4], zs[4];
    #pragma unroll
    for (int u = 0; u < 4; ++u) {
        int g = u * 512 + tid;           // [0, 2048): 64 rows x 32 chunks(16B)
        int r = g >> 5, c = g & 31;
        int i = bm + r;
        int tg = tgtp[i], sr = srcp[i];
        zt[u] = *reinterpret_cast<const bf16x8*>(Z + (size_t)tg * 512 + c * 8);
        zs[u] = *reinterpret_cast<const bf16x8*>(Z + (size_t)sr * 512 + 256 + c * 8);
    }
    // ---- phase 2: fuse (add + bm1 + relu), write As ----
    #pragma unroll
    for (int u = 0; u < 4; ++u) {
        int g = u * 512 + tid;
        int r = g >> 5, c = g & 31;
        PU a, b, o;
        a.v = zt[u]; b.v = zs[u];
        float4 k0v = *reinterpret_cast<const float4*>(kbias + c * 8);
        float4 k1v = *reinterpret_cast<const float4*>(kbias + c * 8 + 4);
        float bb[8] = {k0v.x, k0v.y, k0v.z, k0v.w, k1v.x, k1v.y, k1v.z, k1v.w};
        #pragma unroll
        for (int j = 0; j < 8; ++j) {
            float v = __bfloat162float(a.h[j]) + __bfloat162float(b.h[j]) + bb[j];
            o.h[j] = __float2bfloat16(fmaxf(v, 0.f));
        }
        *reinterpret_cast<bf16x8*>(&As[r * LDA + c * 8]) = o.v;
    }
    __syncthreads();   // the ONLY barrier

    const int wn = w;
    f32x4 acc[4][2];
    #pragma unroll
    for (int mt = 0; mt < 4; ++mt)
        #pragma unroll
        for (int nt = 0; nt < 2; ++nt)
            #pragma unroll
            for (int r = 0; r < 4; ++r) acc[mt][nt][r] = 0.f;

    #pragma unroll
    for (int k0 = 0; k0 < 256; k0 += 32) {
        bf16x8 af[4], bfr[2];
        #pragma unroll
        for (int nt = 0; nt < 2; ++nt)
            bfr[nt] = *reinterpret_cast<const bf16x8*>(
                B + (size_t)(wn * 32 + nt * 16 + l16) * 256 + k0 + quad * 8);
        #pragma unroll
        for (int mt = 0; mt < 4; ++mt)
            af[mt] = *reinterpret_cast<const bf16x8*>(&As[(mt * 16 + l16) * LDA + k0 + quad * 8]);
        #pragma unroll
        for (int mt = 0; mt < 4; ++mt)
            #pragma unroll
            for (int nt = 0; nt < 2; ++nt)
                acc[mt][nt] = __builtin_amdgcn_mfma_f32_16x16x32_bf16(af[mt], bfr[nt], acc[mt][nt], 0, 0, 0);
    }

    #pragma unroll
    for (int mt = 0; mt < 4; ++mt) {
        #pragma unroll
        for (int nt = 0; nt < 2; ++nt) {
            int col = wn * 32 + nt * 16 + l16;
            float bv = bias[col];
            #pragma unroll
            for (int r = 0; r < 4; ++r) {
                int row = bm + mt * 16 + quad * 4 + r;
                float v = fmaxf(acc[mt][nt][r] + bv, 0.f);
                C[(size_t)row * 256 + col] = __float2bfloat16(v);
            }
        }
    }
}

// ---------------------------------------------------------------------------
// Batched (grid.z) 64x64 GEMM slices: M=4096, N=256 (per slice), K=256, ldb=256.
// ---------------------------------------------------------------------------
struct GSet { const __hip_bfloat16* A; int lda; const __hip_bfloat16* B;
              const float* bias; const float* rowscale;
              const float* extra; float esc; float cscale;
              __hip_bfloat16* C; float* Cf; int vtout; int ldc; int coloff; };
struct GPack { GSet s[8]; };

__global__ __launch_bounds__(256) void gemm_bz(GPack p, const int* __restrict__ eidx)
{
    GSet g = p.s[blockIdx.z];
    constexpr int LDT = 40;
    __shared__ alignas(16) __hip_bfloat16 As[64 * LDT];
    __shared__ alignas(16) __hip_bfloat16 Bs[64 * LDT];

    const int tid = threadIdx.x;
    const int w = tid >> 6, lane = tid & 63, l16 = lane & 15, quad = lane >> 4;
    const int wm = w >> 1, wn = w & 1;
    const int bm = blockIdx.y * 64, bn = blockIdx.x * 64;

    f32x4 acc[2][2];
    #pragma unroll
    for (int i = 0; i < 2; ++i)
        #pragma unroll
        for (int j = 0; j < 2; ++j)
            #pragma unroll
            for (int r = 0; r < 4; ++r) acc[i][j][r] = 0.f;

    for (int k0 = 0; k0 < 256; k0 += 32) {
        #pragma unroll
        for (int f = tid; f < 256; f += 256) {
            int r = f >> 2, sg = f & 3;
            *reinterpret_cast<uint4*>(&As[r * LDT + sg * 8]) =
                *reinterpret_cast<const uint4*>(g.A + (size_t)(bm + r) * g.lda + k0 + sg * 8);
            *reinterpret_cast<uint4*>(&Bs[r * LDT + sg * 8]) =
                *reinterpret_cast<const uint4*>(g.B + (size_t)(bn + r) * 256 + k0 + sg * 8);
        }
        __syncthreads();
        bf16x8 af[2], bfr[2];
        #pragma unroll
        for (int mt = 0; mt < 2; ++mt)
            af[mt] = *reinterpret_cast<const bf16x8*>(&As[(wm * 32 + mt * 16 + l16) * LDT + quad * 8]);
        #pragma unroll
        for (int nt = 0; nt < 2; ++nt)
            bfr[nt] = *reinterpret_cast<const bf16x8*>(&Bs[(wn * 32 + nt * 16 + l16) * LDT + quad * 8]);
        #pragma unroll
        for (int mt = 0; mt < 2; ++mt)
            #pragma unroll
            for (int nt = 0; nt < 2; ++nt)
                acc[mt][nt] = __builtin_amdgcn_mfma_f32_16x16x32_bf16(af[mt], bfr[nt], acc[mt][nt], 0, 0, 0);
        __syncthreads();
    }

    #pragma unroll
    for (int mt = 0; mt < 2; ++mt) {
        #pragma unroll
        for (int nt = 0; nt < 2; ++nt) {
            int colL = bn + wn * 32 + nt * 16 + l16;
            #pragma unroll
            for (int r = 0; r < 4; ++r) {
                int row = bm + wm * 32 + mt * 16 + quad * 4 + r;
                float v = acc[mt][nt][r];
                if (g.bias) {
                    float bv = g.bias[colL];
                    if (g.rowscale) bv *= g.rowscale[row];
                    v += bv;
                }
                if (g.extra) v += g.esc * g.extra[(size_t)eidx[row] * QD + colL];
                v *= g.cscale;
                if (g.vtout)
                    g.C[(size_t)colL * 4096 + row] = __float2bfloat16(v);
                else if (g.Cf)
                    g.Cf[(size_t)row * g.ldc + g.coloff + colL] = v;
                else
                    g.C[(size_t)row * g.ldc + g.coloff + colL] = __float2bfloat16(v);
            }
        }
    }
}

// ---------------------------------------------------------------------------
// fp32 tiled composite-weight GEMM (startup): 32x32 tile, BK=16, 2x2 microtile.
// ---------------------------------------------------------------------------
struct FDesc { const float* A; int lda; const float* B; int ldb; int tb;
               const float* bias; float* C; int M, N, K; };
struct FPack { FDesc d[16]; };

__global__ __launch_bounds__(256) void fgemm2(FPack p)
{
    FDesc c = p.d[blockIdx.z];
    int bm = blockIdx.y * 32, bn = blockIdx.x * 32;
    if (bm >= c.M || bn >= c.N) return;
    __shared__ float As[16][33];
    __shared__ float Bs[16][33];
    int tid = threadIdx.x;
    int tr = tid / 16, tc = tid % 16;
    float acc[2][2] = {};

    for (int k0 = 0; k0 < c.K; k0 += 16) {
        #pragma unroll
        for (int u = 0; u < 2; ++u) {
            int i = tid * 2 + u;
            int m = i >> 4, kk = i & 15;
            int row = bm + m, kg = k0 + kk;
            As[kk][m] = (row < c.M && kg < c.K) ? c.A[(size_t)row * c.lda + kg] : 0.f;
        }
        if (c.tb) {
            #pragma unroll
            for (int u = 0; u < 2; ++u) {
                int i = tid * 2 + u;
                int n = i >> 4, kk = i & 15;
                int col = bn + n, kg = k0 + kk;
                Bs[kk][n] = (col < c.N && kg < c.K) ? c.B[(size_t)col * c.ldb + kg] : 0.f;
            }
        } else {
            #pragma unroll
            for (int u = 0; u < 2; ++u) {
                int i = tid * 2 + u;
                int kk = i >> 5, n = i & 31;
                int col = bn + n, kg = k0 + kk;
                Bs[kk][n] = (col < c.N && kg < c.K) ? c.B[(size_t)kg * c.ldb + col] : 0.f;
            }
        }
        __syncthreads();
        #pragma unroll
        for (int kk = 0; kk < 16; ++kk) {
            float a0 = As[kk][tr * 2], a1 = As[kk][tr * 2 + 1];
            float b0 = Bs[kk][tc * 2], b1 = Bs[kk][tc * 2 + 1];
            acc[0][0] = fmaf(a0, b0, acc[0][0]);
            acc[0][1] = fmaf(a0, b1, acc[0][1]);
            acc[1][0] = fmaf(a1, b0, acc[1][0]);
            acc[1][1] = fmaf(a1, b1, acc[1][1]);
        }
        __syncthreads();
    }

    #pragma unroll
    for (int i = 0; i < 2; ++i) {
        int row = bm + tr * 2 + i;
        if (row >= c.M) continue;
        #pragma unroll
        for (int j = 0; j < 2; ++j) {
            int col = bn + tc * 2 + j;
            if (col >= c.N) continue;
            float v = acc[i][j];
            if (c.bias) v += c.bias[col];
            c.C[(size_t)row * c.N + col] = v;
        }
    }
}

// ---------------------------------------------------------------------------
// Flash MHA v10b: 64 q-rows per block (4 q-sets shared by 8 key-split waves),
// 512 threads, grid (64, 8).  Ones-MFMA row-sum (denominator on the matrix
// pipe).  Harness-verified 50.2 us.  16-wave variants spilled (v11);
// key-split atomic merge regressed (v12: 68 us, 72MB atomic traffic).
// ---------------------------------------------------------------------------
__global__ __launch_bounds__(512, 4) void mha_flash10(
    const __hip_bfloat16* __restrict__ Qm,
    const __hip_bfloat16* __restrict__ Km,
    const __hip_bfloat16* __restrict__ Vt, __hip_bfloat16* __restrict__ Out)
{
    const int hh = blockIdx.y;
    const int tid = threadIdx.x;
    const int w = tid >> 6, lane = tid & 63, l16 = lane & 15, quad = lane >> 4;
    const int qb = blockIdx.x * 64;

    __shared__ float Osh[8][4][64][9];   // [9] pad: conflict-free scalar merge
    __shared__ float Lsh[8][4][16];

    bf16x8 aq[4];
    #pragma unroll
    for (int s = 0; s < 4; ++s)
        aq[s] = *reinterpret_cast<const bf16x8*>(
            Qm + (size_t)(qb + s * 16 + l16) * 256 + hh * 32 + quad * 8);
    const __hip_bfloat16* vb0 = Vt + (size_t)(hh * 32 + l16) * 4096;
    const __hip_bfloat16* vb1 = vb0 + (size_t)16 * 4096;
    const int rowoff = (l16 >> 2) * 8 + (l16 & 3);
    const f32x4 zero = {0.f, 0.f, 0.f, 0.f};

    PU onesu;
    #pragma unroll
    for (int j = 0; j < 8; ++j) onesu.h[j] = __float2bfloat16(1.f);
    const bf16x8 onesv = onesu.v;

    f32x4 o0[4], o1[4], lac[4];
    #pragma unroll
    for (int s = 0; s < 4; ++s) { o0[s] = zero; o1[s] = zero; lac[s] = zero; }

    const int kstart = w * 512;
    for (int kt = 0; kt < 8; ++kt) {
        const int kbase = kstart + kt * 64;
        bf16x8 kf[4];
        #pragma unroll
        for (int c = 0; c < 2; ++c)
            #pragma unroll
            for (int st = 0; st < 2; ++st)
                kf[c * 2 + st] = *reinterpret_cast<const bf16x8*>(
                    Km + (size_t)(kbase + c * 32 + st * 4 + rowoff) * 256 + hh * 32 + quad * 8);
        bf16x8 v00 = *reinterpret_cast<const bf16x8*>(vb0 + kbase + quad * 8);
        bf16x8 v01 = *reinterpret_cast<const bf16x8*>(vb1 + kbase + quad * 8);
        bf16x8 v10 = *reinterpret_cast<const bf16x8*>(vb0 + kbase + 32 + quad * 8);
        bf16x8 v11 = *reinterpret_cast<const bf16x8*>(vb1 + kbase + 32 + quad * 8);

        #pragma unroll
        for (int s = 0; s < 4; ++s) {
            f32x4 sv[4];
            __builtin_amdgcn_s_setprio(1);
            #pragma unroll
            for (int i = 0; i < 4; ++i)
                sv[i] = __builtin_amdgcn_mfma_f32_16x16x32_bf16(kf[i], aq[s], zero, 0, 0, 0);
            __builtin_amdgcn_s_setprio(0);
            PU p0, p1;
            #pragma unroll
            for (int i = 0; i < 4; ++i) {
                float e0 = exp2f(sv[i][0]), e1 = exp2f(sv[i][1]);
                float e2 = exp2f(sv[i][2]), e3 = exp2f(sv[i][3]);
                PU& pp = (i < 2) ? p0 : p1;
                pp.b2[(i & 1) * 2 + 0] = __float22bfloat162_rn(make_float2(e0, e1));
                pp.b2[(i & 1) * 2 + 1] = __float22bfloat162_rn(make_float2(e2, e3));
            }
            __builtin_amdgcn_s_setprio(1);
            o0[s]  = __builtin_amdgcn_mfma_f32_16x16x32_bf16(v00,   p0.v, o0[s],  0, 0, 0);
            o1[s]  = __builtin_amdgcn_mfma_f32_16x16x32_bf16(v01,   p0.v, o1[s],  0, 0, 0);
            lac[s] = __builtin_amdgcn_mfma_f32_16x16x32_bf16(onesv, p0.v, lac[s], 0, 0, 0);
            o0[s]  = __builtin_amdgcn_mfma_f32_16x16x32_bf16(v10,   p1.v, o0[s],  0, 0, 0);
            o1[s]  = __builtin_amdgcn_mfma_f32_16x16x32_bf16(v11,   p1.v, o1[s],  0, 0, 0);
            lac[s] = __builtin_amdgcn_mfma_f32_16x16x32_bf16(onesv, p1.v, lac[s], 0, 0, 0);
            __builtin_amdgcn_s_setprio(0);
        }
    }

    // lac rows are all identical (= sum over this wave's keys for q-col l16)
    float lsum[4];
    #pragma unroll
    for (int s = 0; s < 4; ++s) lsum[s] = lac[s][0];

    #pragma unroll
    for (int s = 0; s < 4; ++s) {
        #pragma unroll
        for (int r = 0; r < 4; ++r) {
            Osh[w][s][lane][r]     = o0[s][r];
            Osh[w][s][lane][4 + r] = o1[s][r];
        }
        if (quad == 0) Lsh[w][s][l16] = lsum[s];
    }
    __syncthreads();
    if (w < 4) {
        const int s = w;
        f32x4 a0 = zero, a1 = zero;
        float ll = 0.f;
        #pragma unroll
        for (int ww = 0; ww < 8; ++ww) {
            #pragma unroll
            for (int r = 0; r < 4; ++r) {
                a0[r] += Osh[ww][s][lane][r];
                a1[r] += Osh[ww][s][lane][4 + r];
            }
            ll += Lsh[ww][s][l16];
        }
        float inv = 1.f / ll;
        __hip_bfloat16* dst = Out + (size_t)(qb + s * 16 + l16) * 256 + hh * 32;
        #pragma unroll
        for (int r = 0; r < 4; ++r) {
            dst[quad * 4 + r]      = __float2bfloat16(a0[r] * inv);
            dst[16 + quad * 4 + r] = __float2bfloat16(a1[r] * inv);
        }
    }
}

// build mask bitfield + per-target degree count in one pass
__global__ __launch_bounds__(256) void build_mask(const int* __restrict__ src,
                                                  const int* __restrict__ tgt,
                                                  unsigned* __restrict__ mb,
                                                  int* __restrict__ cnt)
{
    int e = blockIdx.x * 256 + threadIdx.x;
    if (e >= E_EDGES) return;
    int t = tgt[e];
    atomicOr(mb + (size_t)src[e] * (N_NODES / 32) + (t >> 5), 1u << (t & 31));
    atomicAdd(&cnt[t], 1);
}

__global__ __launch_bounds__(1024) void csr_scan(const int* __restrict__ cnt, int* __restrict__ off,
                                                 int* __restrict__ cursor, float* __restrict__ degf)
{
    __shared__ int sh[1024];
    int t = threadIdx.x;
    int base = t * 4;
    int c0 = cnt[base], c1 = cnt[base + 1], c2 = cnt[base + 2], c3 = cnt[base + 3];
    int sum = c0 + c1 + c2 + c3;
    sh[t] = sum; __syncthreads();
    for (int d = 1; d < 1024; d <<= 1) {
        int v = (t >= d) ? sh[t - d] : 0;
        __syncthreads();
        sh[t] += v;
        __syncthreads();
    }
    int excl = sh[t] - sum;
    int o0 = excl, o1 = excl + c0, o2 = o1 + c1, o3 = o2 + c2;
    off[base] = o0; off[base + 1] = o1; off[base + 2] = o2; off[base + 3] = o3;
    cursor[base] = o0; cursor[base + 1] = o1; cursor[base + 2] = o2; cursor[base + 3] = o3;
    degf[base] = (float)c0; degf[base + 1] = (float)c1;
    degf[base + 2] = (float)c2; degf[base + 3] = (float)c3;
    if (t == 1023) off[4096] = sh[t];
}

__global__ __launch_bounds__(256) void csr_fill(const int* __restrict__ src, const int* __restrict__ tgt,
                                                int* __restrict__ cursor,
                                                int* __restrict__ srcp, int* __restrict__ tgtp)
{
    int e = blockIdx.x * 256 + threadIdx.x;
    if (e >= E_EDGES) return;
    int t = tgt[e];
    int pos = atomicAdd(&cursor[t], 1);
    srcp[pos] = src[e];
    tgtp[pos] = t;
}

__global__ __launch_bounds__(256) void seg_sum(const int* __restrict__ off,
                                               const __hip_bfloat16* __restrict__ M2,
                                               __hip_bfloat16* __restrict__ A3)
{
    int n = blockIdx.x, t = threadIdx.x;
    int b0 = off[n], b1 = off[n + 1];
    float s = 0.f;
    for (int i = b0; i < b1; ++i)
        s += __bfloat162float(M2[(size_t)i * 256 + t]);
    A3[(size_t)n * 256 + t] = __float2bfloat16(s);
}

// Sparse graph-masked attention over bf16 Q,K,V. Writes out (=).
__global__ __launch_bounds__(256) void sparse_attn(
    const __hip_bfloat16* __restrict__ Q, const __hip_bfloat16* __restrict__ K,
    const __hip_bfloat16* __restrict__ V, int vld,
    const unsigned* __restrict__ maskb, float* __restrict__ outb)
{
    int i = blockIdx.x, t = threadIdx.x;
    __shared__ float qsh[256];
    __shared__ int   nb[1024];
    __shared__ float sc[1024];
    __shared__ int   cnt;
    __shared__ float red[4];
    __shared__ float smax, ssum;
    if (t == 0) cnt = 0;
    qsh[t] = __bfloat162float(Q[(size_t)i * 256 + t]);
    __syncthreads();
    if (t < 128) {
        unsigned wv = maskb[(size_t)i * 128 + t];
        while (wv) {
            int b = __ffs(wv) - 1; wv &= wv - 1;
            int p = atomicAdd(&cnt, 1);
            nb[p] = t * 32 + b;
        }
    }
    __syncthreads();
    int deg = cnt;
    int wid = t >> 6, lane = t & 63;
    if (deg > 0) {
        for (int n = wid; n < deg; n += 4) {
            union { uint2 u; __hip_bfloat16 h[4]; } kv;
            kv.u = *reinterpret_cast<const uint2*>(K + (size_t)nb[n] * 256 + lane * 4);
            float s = qsh[lane*4+0] * __bfloat162float(kv.h[0]) + qsh[lane*4+1] * __bfloat162float(kv.h[1])
                    + qsh[lane*4+2] * __bfloat162float(kv.h[2]) + qsh[lane*4+3] * __bfloat162float(kv.h[3]);
            #pragma unroll
            for (int off = 32; off; off >>= 1) s += __shfl_xor(s, off);
            if (lane == 0) sc[n] = s * 0.0625f;
        }
        __syncthreads();
        float m = -3.4e38f;
        for (int n = t; n < deg; n += 256) m = fmaxf(m, sc[n]);
        #pragma unroll
        for (int off = 32; off; off >>= 1) m = fmaxf(m, __shfl_xor(m, off));
        if (lane == 0) red[wid] = m;
        __syncthreads();
        if (t == 0) smax = fmaxf(fmaxf(red[0], red[1]), fmaxf(red[2], red[3]));
        __syncthreads();
        float ls = 0.f;
        for (int n = t; n < deg; n += 256) { float e = __expf(sc[n] - smax); sc[n] = e; ls += e; }
        #pragma unroll
        for (int off = 32; off; off >>= 1) ls += __shfl_xor(ls, off);
        if (lane == 0) red[wid] = ls;
        __syncthreads();
        if (t == 0) ssum = red[0] + red[1] + red[2] + red[3];
        __syncthreads();
        float inv = 1.f / ssum;
        float o = 0.f;
        for (int n = 0; n < deg; ++n)
            o += sc[n] * __bfloat162float(V[(size_t)nb[n] * vld + t]);
        outb[(size_t)i * 256 + t] = o * inv;
    } else {
        float o = 0.f;
        for (int j = 0; j < N_NODES; ++j) o += __bfloat162float(V[(size_t)j * vld + t]);
        outb[(size_t)i * 256 + t] = o * (1.f / N_NODES);
    }
}

// h = LN(h + a1 + a2 + a3)
__global__ __launch_bounds__(256) void ln_kernel(float* __restrict__ h, __hip_bfloat16* __restrict__ h16,
                                                 const float* __restrict__ a1,
                                                 const float* __restrict__ a2,
                                                 const float* __restrict__ a3,
                                                 const float* __restrict__ g, const float* __restrict__ b)
{
    int row = blockIdx.x, t = threadIdx.x;
    __shared__ float red[256];
    size_t off = ((size_t)row << 8) + t;
    float v = h[off] + a1[off] + a2[off] + a3[off];
    red[t] = v; __syncthreads();
    for (int s = 128; s > 0; s >>= 1) { if (t < s) red[t] += red[t + s]; __syncthreads(); }
    float mu = red[0] * (1.f / 256.f); __syncthreads();
    float d = v - mu;
    red[t] = d * d; __syncthreads();
    for (int s = 128; s > 0; s >>= 1) { if (t < s) red[t] += red[t + s]; __syncthreads(); }
    float var = red[0] * (1.f / 256.f);
    float r = d * rsqrtf(var + 1e-5f) * g[t] + b[t];
    h[off] = r;
    h16[off] = __float2bfloat16(r);
}

__global__ __launch_bounds__(256) void colpool(const float* __restrict__ h, float* __restrict__ p)
{
    int c = blockIdx.x, t = threadIdx.x;
    __shared__ float rs[256], rm[256];
    float s = 0.f, m = -3.4e38f;
    for (int row = t; row < N_NODES; row += 256) {
        float v = h[((size_t)row << 8) + c];
        s += v; m = fmaxf(m, v);
    }
    rs[t] = s; rm[t] = m; __syncthreads();
    for (int st = 128; st > 0; st >>= 1) {
        if (t < st) { rs[t] += rs[t + st]; rm[t] = fmaxf(rm[t], rm[t + st]); }
        __syncthreads();
    }
    if (t == 0) { p[c] = rs[0] * (1.f / N_NODES); p[256 + c] = rm[0]; }
}

__global__ __launch_bounds__(256) void classifier(const float* __restrict__ pooled,
                                                  const float* __restrict__ Wc1, const float* __restrict__ bc1,
                                                  const float* __restrict__ Wc2, const float* __restrict__ bc2,
                                                  float* __restrict__ out)
{
    __shared__ float p[512];
    __shared__ float z[256];
    int t = threadIdx.x;
    p[t] = pooled[t]; p[256 + t] = pooled[256 + t];
    __syncthreads();
    float s = bc1[t];
    for (int k = 0; k < 512; ++k) s = fmaf(p[k], Wc1[k * 256 + t], s);
    z[t] = fmaxf(s, 0.f);
    __syncthreads();
    if (t < OUT_F) {
        float o = bc2[t];
        for (int j = 0; j < 256; ++j) o = fmaf(z[j], Wc2[j * OUT_F + t], o);
        out[t] = o;
    }
}

// ---- bf16 conversion ----
struct CDesc { const float* s; __hip_bfloat16* d; int total; };
struct CPack { CDesc d[2]; };
__global__ __launch_bounds__(256) void convert_copy(CPack p)
{
    CDesc c = p.d[blockIdx.y];
    for (int i = blockIdx.x * 256 + threadIdx.x; i < c.total; i += gridDim.x * 256)
        c.d[i] = __float2bfloat16(c.s[i]);
}
// LDS-tiled transpose-convert: d[n*K+k] = bf16(s[k*sld+n]); coalesced both sides
struct TDesc { const float* s; __hip_bfloat16* d; int K, N, sld; };
struct TPack { TDesc d[23]; };
__global__ __launch_bounds__(256) void convert_t32(TPack p)
{
    TDesc c = p.d[blockIdx.z];
    int k0 = blockIdx.x * 32, n0 = blockIdx.y * 32;
    if (k0 >= c.K || n0 >= c.N) return;
    __shared__ float t[32][33];
    int tr = threadIdx.x >> 5, tc = threadIdx.x & 31;
    #pragma unroll
    for (int rr = 0; rr < 32; rr += 8)
        t[tc][tr + rr] = c.s[(size_t)(k0 + tr + rr) * c.sld + n0 + tc];
    __syncthreads();
    #pragma unroll
    for (int rr = 0; rr < 32; rr += 8)
        c.d[(size_t)(n0 + tr + rr) * c.K + k0 + tc] = __float2bfloat16(t[tr + rr][tc]);
}

extern "C" void kernel_launch(void* const* d_in, const int* in_sizes, int n_in,
                              void* d_out, int out_size, void* d_ws, size_t ws_size,
                              hipStream_t stream)
{
    const float* x    = (const float*)d_in[0];
    const int*   ei   = (const int*)d_in[1];
    const int*   ct   = (const int*)d_in[2];
    const float* Wi   = (const float*)d_in[3];
    const float* bi   = (const float*)d_in[4];
    const float* Wq   = (const float*)d_in[5];
    const float* bq   = (const float*)d_in[6];
    const float* Wk   = (const float*)d_in[7];
    const float* bk   = (const float*)d_in[8];
    const float* Wv   = (const float*)d_in[9];
    const float* bv   = (const float*)d_in[10];
    const float* Bc   = (const float*)d_in[11];
    const float* cemb = (const float*)d_in[12];
    const float* Win  = (const float*)d_in[13];
    const float* binp = (const float*)d_in[14];
    const float* Wo   = (const float*)d_in[15];
    const float* bo   = (const float*)d_in[16];
    const float* Wm1  = (const float*)d_in[17];
    const float* bm1  = (const float*)d_in[18];
    const float* Wm2  = (const float*)d_in[19];
    const float* bm2  = (const float*)d_in[20];
    const float* Wm3  = (const float*)d_in[21];
    const float* bm3  = (const float*)d_in[22];
    const float* lng  = (const float*)d_in[23];
    const float* lnb  = (const float*)d_in[24];
    const float* Wc1  = (const float*)d_in[25];
    const float* bc1  = (const float*)d_in[26];
    const float* Wc2  = (const float*)d_in[27];
    const float* bc2  = (const float*)d_in[28];

    const int* src = ei;
    const int* tgt = ei + E_EDGES;

    // ---- workspace carve-up ----
    char* wp = (char*)d_ws;
    auto alloc = [&](size_t bytes) { char* r = wp; wp += (bytes + 255) & ~(size_t)255; return r; };
    const size_t NH = (size_t)N_NODES * 256;
    float* h      = (float*)alloc(NH * 4);
    float* a1     = (float*)alloc(NH * 4);
    float* a2     = (float*)alloc(NH * 4);
    float* a3     = (float*)alloc(NH * 4);
    float* pooled = (float*)alloc(512 * 4);
    float* degf   = (float*)alloc(N_NODES * 4);
    __hip_bfloat16* x16 = (__hip_bfloat16*)alloc((size_t)N_NODES * 512 * 2);
    __hip_bfloat16* h16 = (__hip_bfloat16*)alloc(NH * 2);
    __hip_bfloat16* Qb  = (__hip_bfloat16*)alloc(NH * 2);
    __hip_bfloat16* Kb  = (__hip_bfloat16*)alloc(NH * 2);
    __hip_bfloat16* Vb  = (__hip_bfloat16*)alloc(NH * 2);
    __hip_bfloat16* Tq  = (__hip_bfloat16*)alloc(NH * 2);
    __hip_bfloat16* Tk  = (__hip_bfloat16*)alloc(NH * 2);
    __hip_bfloat16* Vt  = (__hip_bfloat16*)alloc(NH * 2);
    __hip_bfloat16* Z12 = (__hip_bfloat16*)alloc((size_t)N_NODES * 512 * 2);
    __hip_bfloat16* M216= (__hip_bfloat16*)alloc((size_t)E_EDGES * 256 * 2);
    __hip_bfloat16* A3  = (__hip_bfloat16*)alloc(NH * 2);
    __hip_bfloat16* Wi_t= (__hip_bfloat16*)alloc((size_t)256 * 512 * 2);
    // fp32 composite weights / biases / ce-tables, per layer
    float *Wqc_f[2], *Wkc_f[2], *Wqm_f[2], *Wkm_f[2], *Wvm_f[2];
    float *bqc[2], *bkc[2], *bqm[2], *bkm[2], *bvm[2], *ceq2[2], *cek2[2];
    for (int l = 0; l < 2; ++l) {
        Wqc_f[l] = (float*)alloc(65536 * 4); Wkc_f[l] = (float*)alloc(65536 * 4);
        Wqm_f[l] = (float*)alloc(65536 * 4); Wkm_f[l] = (float*)alloc(65536 * 4);
        Wvm_f[l] = (float*)alloc(65536 * 4);
        bqc[l] = (float*)alloc(256 * 4); bkc[l] = (float*)alloc(256 * 4);
        bqm[l] = (float*)alloc(256 * 4); bkm[l] = (float*)alloc(256 * 4);
        bvm[l] = (float*)alloc(256 * 4);
        ceq2[l] = (float*)alloc(CT_N * 256 * 4); cek2[l] = (float*)alloc(CT_N * 256 * 4);
    }
    // bf16 [N][K] weights: per layer: Wqc,Wkc,Wqm,Wkm,Wvm,Wv,Wo,Wm1a,Wm1b,Wm2,Wm3
    __hip_bfloat16* WB[2][11];
    for (int l = 0; l < 2; ++l)
        for (int m = 0; m < 11; ++m)
            WB[l][m] = (__hip_bfloat16*)alloc(65536 * 2);
    unsigned* maskb = (unsigned*)alloc((size_t)N_NODES * 128 * 4);
    int* cnt    = (int*)alloc(N_NODES * 4);
    int* cursor = (int*)alloc(N_NODES * 4);
    int* off    = (int*)alloc((N_NODES + 1) * 4);
    int* srcp   = (int*)alloc(E_EDGES * 4);
    int* tgtp   = (int*)alloc(E_EDGES * 4);

    // ---- startup: x conversion ----
    CPack cp; cp.d[0] = {x, x16, N_NODES * 512};
    convert_copy<<<dim3(256, 1), 256, 0, stream>>>(cp);

    // ---- composite fp32 weights (tiled fgemm2, 2 dependent waves) ----
    FPack f1; int n1 = 0;
    FPack f2; int n2 = 0;
    for (int l = 0; l < 2; ++l) {
        const float* Wq_l  = Wq + (size_t)l * 65536;
        const float* Wk_l  = Wk + (size_t)l * 65536;
        const float* Wv_l  = Wv + (size_t)l * 65536;
        const float* Bc_l  = Bc + (size_t)l * 65536;
        const float* Win_l = Win + (size_t)l * 256 * 768;
        const float* ce_l  = cemb + (size_t)l * CT_N * QD;
        const float* bq_l  = bq + l * 256;
        const float* bk_l  = bk + l * 256;
        const float* bv_l  = bv + l * 256;
        const float* bin_l = binp + l * 768;
        f1.d[n1++] = {Wq_l, 256, Bc_l, 256, 0, nullptr, Wqc_f[l], 256, 256, 256};
        f1.d[n1++] = {Wk_l, 256, Bc_l, 256, 1, nullptr, Wkc_f[l], 256, 256, 256};
        f1.d[n1++] = {bq_l, 256, Bc_l, 256, 0, nullptr, bqc[l], 1, 256, 256};
        f1.d[n1++] = {bk_l, 256, Bc_l, 256, 1, nullptr, bkc[l], 1, 256, 256};
        f2.d[n2++] = {Wqc_f[l], 256, Win_l,       768, 0, nullptr, Wqm_f[l], 256, 256, 256};
        f2.d[n2++] = {Wkc_f[l], 256, Win_l + 256, 768, 0, nullptr, Wkm_f[l], 256, 256, 256};
        f2.d[n2++] = {Wv_l,     256, Win_l + 512, 768, 0, nullptr, Wvm_f[l], 256, 256, 256};
        f2.d[n2++] = {ce_l,     256, Win_l,       768, 0, nullptr, ceq2[l], CT_N, 256, 256};
        f2.d[n2++] = {ce_l,     256, Win_l + 256, 768, 0, nullptr, cek2[l], CT_N, 256, 256};
        f2.d[n2++] = {bqc[l],   256, Win_l,       768, 0, bin_l,       bqm[l], 1, 256, 256};
        f2.d[n2++] = {bkc[l],   256, Win_l + 256, 768, 0, bin_l + 256, bkm[l], 1, 256, 256};
        f2.d[n2++] = {bv_l,     256, Win_l + 512, 768, 0, bin_l + 512, bvm[l], 1, 256, 256};
    }
    fgemm2<<<dim3(8, 8, n1), 256, 0, stream>>>(f1);
    fgemm2<<<dim3(8, 8, n2), 256, 0, stream>>>(f2);

    // ---- transpose-convert all [K][N] fp32 weights to bf16 [N][K] ----
    TPack tp; int ndt = 0;
    auto addT = [&](const float* s, __hip_bfloat16* d, int K, int N, int sld) { tp.d[ndt++] = {s, d, K, N, sld}; };
    addT(Wi, Wi_t, 512, 256, 256);
    for (int l = 0; l < 2; ++l) {
        const float* Wv_l  = Wv + (size_t)l * 65536;
        const float* Wo_l  = Wo + (size_t)l * 65536;
        const float* Wm1_l = Wm1 + (size_t)l * (2 * H_F + QD) * QD;  // layer stride 768*256!
        const float* Wm2_l = Wm2 + (size_t)l * 65536;
        const float* Wm3_l = Wm3 + (size_t)l * 65536;
        addT(Wqc_f[l], WB[l][0], 256, 256, 256);
        addT(Wkc_f[l], WB[l][1], 256, 256, 256);
        addT(Wqm_f[l], WB[l][2], 256, 256, 256);
        addT(Wkm_f[l], WB[l][3], 256, 256, 256);
        addT(Wvm_f[l], WB[l][4], 256, 256, 256);
        addT(Wv_l,     WB[l][5], 256, 256, 256);
        addT(Wo_l,     WB[l][6], 256, 256, 256);
        addT(Wm1_l,             WB[l][7], 256, 256, 256);
        addT(Wm1_l + 256 * 256, WB[l][8], 256, 256, 256);
        addT(Wm2_l,    WB[l][9],  256, 256, 256);
        addT(Wm3_l,    WB[l][10], 256, 256, 256);
    }
    convert_t32<<<dim3(16, 8, ndt), 256, 0, stream>>>(tp);

    hipMemsetAsync(maskb, 0, (size_t)N_NODES * 128 * 4, stream);
    hipMemsetAsync(cnt, 0, N_NODES * 4, stream);
    build_mask<<<E_EDGES / 256, 256, 0, stream>>>(src, tgt, maskb, cnt);
    csr_scan<<<1, 1024, 0, stream>>>(cnt, off, cursor, degf);
    csr_fill<<<E_EDGES / 256, 256, 0, stream>>>(src, tgt, cursor, srcp, tgtp);

    // h = relu(x @ Wi + bi)
    gemm_mfma<64, 64, false><<<dim3(4, 64), 256, 0, stream>>>(
        x16, 512, Wi_t, 512, h, h16, 256, 512,
        bi, nullptr, nullptr, nullptr, nullptr, FLAG_RELU | FLAG_WF32 | FLAG_WB16);

    const float QSCALE = 0.25507693f;   // log2(e)/sqrt(32)

    for (int l = 0; l < L_LAYERS; ++l) {
        const float* ce_l  = cemb + (size_t)l * CT_N * QD;
        const float* bo_l  = bo + l * QD;
        const float* bm1_l = bm1 + l * QD;
        const float* bm2_l = bm2 + l * QD;
        const float* bm3_l = bm3 + l * H_F;
        const float* lng_l = lng + l * H_F;
        const float* lnb_l = lnb + l * H_F;
        const float* bv_l  = bv + l * 256;

        // ---- one z=8 projection launch from h ----
        {
            GPack gp;
            gp.s[0] = {h16, 256, WB[l][0], bqc[l], nullptr, ce_l,    0.1f, 1.0f,   Qb,  nullptr, 0, 256, 0};
            gp.s[1] = {h16, 256, WB[l][1], bkc[l], nullptr, ce_l,    0.1f, 1.0f,   Kb,  nullptr, 0, 256, 0};
            gp.s[2] = {h16, 256, WB[l][5], bv_l,   nullptr, nullptr, 0.f,  1.0f,   Vb,  nullptr, 0, 256, 0};
            gp.s[3] = {h16, 256, WB[l][2], bqm[l], nullptr, ceq2[l], 0.1f, QSCALE, Tq,  nullptr, 0, 256, 0};
            gp.s[4] = {h16, 256, WB[l][3], bkm[l], nullptr, cek2[l], 0.1f, 1.0f,   Tk,  nullptr, 0, 256, 0};
            gp.s[5] = {h16, 256, WB[l][4], bvm[l], nullptr, nullptr, 0.f,  1.0f,   Vt,  nullptr, 1, 256, 0};
            gp.s[6] = {h16, 256, WB[l][7], nullptr, nullptr, nullptr, 0.f, 1.0f,   Z12, nullptr, 0, 512, 0};
            gp.s[7] = {h16, 256, WB[l][8], nullptr, nullptr, nullptr, 0.f, 1.0f,   Z12, nullptr, 0, 512, 256};
            gemm_bz<<<dim3(4, 64, 8), 256, 0, stream>>>(gp, ct);
        }

        // sparse graph-masked attention -> a1
        sparse_attn<<<N_NODES, 256, 0, stream>>>(Qb, Kb, Vb, 256, maskb, a1);

        // flash MHA v10b (64 q-rows/block, 8 waves, ones-MFMA row-sum): heads -> Qb
        mha_flash10<<<dim3(64, NHEAD), 512, 0, stream>>>(Tq, Tk, Vt, Qb);

        // edge MLP: gather-once full-K, barrier-free K-loop -> M216, seg-sum -> A3
        edge_gemm<<<E_EDGES / 64, 512, 0, stream>>>(
            Z12, WB[l][9], M216, tgtp, srcp, bm1_l, bm2_l);
        seg_sum<<<N_NODES, 256, 0, stream>>>(off, M216, A3);

        // batched fp32 outputs: a2 = heads@Wo + bo ; a3 = A3@Wm3 + deg*bm3
        {
            GPack gp;
            gp.s[0] = {Qb, 256, WB[l][6],  bo_l,  nullptr, nullptr, 0.f, 1.0f, nullptr, a2, 0, 256, 0};
            gp.s[1] = {A3, 256, WB[l][10], bm3_l, degf,    nullptr, 0.f, 1.0f, nullptr, a3, 0, 256, 0};
            gemm_bz<<<dim3(4, 64, 2), 256, 0, stream>>>(gp, ct);
        }

        // h = LN(h + a1 + a2 + a3)
        ln_kernel<<<N_NODES, 256, 0, stream>>>(h, h16, a1, a2, a3, lng_l, lnb_l);
    }

    colpool<<<H_F, 256, 0, stream>>>(h, pooled);
    classifier<<<1, 256, 0, stream>>>(pooled, Wc1, bc1, Wc2, bc2, (float*)d_out);
}

// Round 8
// 500.102 us; speedup vs baseline: 1.1343x; 1.0340x over previous
//
#include <hip/hip_runtime.h>
#include <hip/hip_bf16.h>

#define N_NODES 4096
#define E_EDGES 65536
#define IN_F    512
#define H_F     256
#define QD      256
#define NHEAD   8
#define HD      32
#define OUT_F   10
#define L_LAYERS 2
#define CT_N    50

enum { FLAG_RELU = 1, FLAG_ACCUM = 2, FLAG_WF32 = 4, FLAG_WB16 = 8 };

typedef __attribute__((ext_vector_type(8))) __bf16 bf16x8;
typedef __attribute__((ext_vector_type(4))) float f32x4;

union PU { bf16x8 v; __hip_bfloat16 h[8]; __hip_bfloat162 b2[4]; };

// ---------------------------------------------------------------------------
// bf16 MFMA GEMM.  A: bf16 [M][K] row-major (lda).  B: bf16 [N][K] (B^T layout).
// ---------------------------------------------------------------------------
template<int BM, int BN, bool EDGE>
__global__ __launch_bounds__(256) void gemm_mfma(
    const __hip_bfloat16* __restrict__ A, int lda,
    const __hip_bfloat16* __restrict__ B, int ldb,
    float* __restrict__ Cf, __hip_bfloat16* __restrict__ Cb, int ldc,
    int K,
    const float* __restrict__ bias, const float* __restrict__ rowscale,
    const int* __restrict__ tgtp, const int* __restrict__ srcp,
    const float* __restrict__ kbias,
    int flags)
{
    constexpr int WM = BM / 2, WN = BN / 2, MT = WM / 16, NT = WN / 16;
    constexpr int LDT = 40;   // 80B row stride -> max 2-way bank alias (free, m136)
    __shared__ alignas(16) __hip_bfloat16 As[BM * LDT];
    __shared__ alignas(16) __hip_bfloat16 Bs[BN * LDT];

    const int tid = threadIdx.x;
    const int w = tid >> 6, lane = tid & 63, l16 = lane & 15, quad = lane >> 4;
    const int wm = w >> 1, wn = w & 1;
    const int bm = blockIdx.y * BM, bn = blockIdx.x * BN;

    f32x4 acc[MT][NT];
    #pragma unroll
    for (int i = 0; i < MT; ++i)
        #pragma unroll
        for (int j = 0; j < NT; ++j)
            #pragma unroll
            for (int r = 0; r < 4; ++r) acc[i][j][r] = 0.f;

    for (int k0 = 0; k0 < K; k0 += 32) {
        #pragma unroll
        for (int f = tid; f < BM * 4; f += 256) {
            int r = f >> 2, sg = f & 3;
            if (EDGE) {
                int i = bm + r;
                int tg = tgtp[i], sr = srcp[i];
                PU z1, z2, o;
                z1.v = *reinterpret_cast<const bf16x8*>(A + (size_t)tg * 512 + k0 + sg * 8);
                z2.v = *reinterpret_cast<const bf16x8*>(A + (size_t)sr * 512 + 256 + k0 + sg * 8);
                float4 b0 = *reinterpret_cast<const float4*>(kbias + k0 + sg * 8);
                float4 b1 = *reinterpret_cast<const float4*>(kbias + k0 + sg * 8 + 4);
                float bb[8] = {b0.x, b0.y, b0.z, b0.w, b1.x, b1.y, b1.z, b1.w};
                #pragma unroll
                for (int j = 0; j < 8; ++j) {
                    float v = __bfloat162float(z1.h[j]) + __bfloat162float(z2.h[j]) + bb[j];
                    o.h[j] = __float2bfloat16(fmaxf(v, 0.f));
                }
                *reinterpret_cast<bf16x8*>(&As[r * LDT + sg * 8]) = o.v;
            } else {
                *reinterpret_cast<uint4*>(&As[r * LDT + sg * 8]) =
                    *reinterpret_cast<const uint4*>(A + (size_t)(bm + r) * lda + k0 + sg * 8);
            }
        }
        #pragma unroll
        for (int f = tid; f < BN * 4; f += 256) {
            int r = f >> 2, sg = f & 3;
            *reinterpret_cast<uint4*>(&Bs[r * LDT + sg * 8]) =
                *reinterpret_cast<const uint4*>(B + (size_t)(bn + r) * ldb + k0 + sg * 8);
        }
        __syncthreads();
        bf16x8 af[MT], bfr[NT];
        #pragma unroll
        for (int mt = 0; mt < MT; ++mt)
            af[mt] = *reinterpret_cast<const bf16x8*>(&As[(wm * WM + mt * 16 + l16) * LDT + quad * 8]);
        #pragma unroll
        for (int nt = 0; nt < NT; ++nt)
            bfr[nt] = *reinterpret_cast<const bf16x8*>(&Bs[(wn * WN + nt * 16 + l16) * LDT + quad * 8]);
        #pragma unroll
        for (int mt = 0; mt < MT; ++mt)
            #pragma unroll
            for (int nt = 0; nt < NT; ++nt)
                acc[mt][nt] = __builtin_amdgcn_mfma_f32_16x16x32_bf16(af[mt], bfr[nt], acc[mt][nt], 0, 0, 0);
        __syncthreads();
    }

    #pragma unroll
    for (int mt = 0; mt < MT; ++mt) {
        #pragma unroll
        for (int nt = 0; nt < NT; ++nt) {
            int col = bn + wn * WN + nt * 16 + l16;
            #pragma unroll
            for (int r = 0; r < 4; ++r) {
                int row = bm + wm * WM + mt * 16 + quad * 4 + r;
                float v = acc[mt][nt][r];
                if (bias) {
                    float bv = bias[col];
                    if (rowscale) bv *= rowscale[row];
                    v += bv;
                }
                if (flags & FLAG_RELU) v = fmaxf(v, 0.f);
                size_t off = (size_t)row * ldc + col;
                if (flags & FLAG_ACCUM)     Cf[off] += v;
                else if (flags & FLAG_WF32) Cf[off] = v;
                if (flags & FLAG_WB16)      Cb[off] = __float2bfloat16(v);
            }
        }
    }
}

// ---------------------------------------------------------------------------
// Edge-MLP GEMM v3 (fused seg-sum): computes the 64x256 M2 tile
// (relu(relu(Z[tgt]+Z[src]+bm1)@Wm2+bm2)) and directly segment-sums it into
// fp32 A3f via CSR-run atomics — eliminates the 32MB M216 write + 32MB
// seg_sum re-read and the serial seg_sum kernel.  tgtp is CSR-sorted, so
// each block's 64 rows hold ~5 contiguous target runs (~1.5K atomics/block,
// ~5MB total vs 64MB round-trip).  B read direct from L2 (128KB, resident).
// ---------------------------------------------------------------------------
__global__ __launch_bounds__(512, 4) void edge_gemm(
    const __hip_bfloat16* __restrict__ Z,   // [N][512] bf16 (Z12)
    const __hip_bfloat16* __restrict__ B,   // Wm2^T [256][256] bf16
    float* __restrict__ A3f,                // [N][256] fp32 accumulator (zeroed)
    const int* __restrict__ tgtp, const int* __restrict__ srcp,
    const float* __restrict__ kbias,        // bm1 [256]
    const float* __restrict__ bias)         // bm2 [256]
{
    constexpr int LDA = 264;   // 256 + 8 pad
    __shared__ alignas(16) __hip_bfloat16 As[64 * LDA];    // 33,792 B
    __shared__ int tg_sh[64];

    const int tid = threadIdx.x;
    const int w = tid >> 6, lane = tid & 63, l16 = lane & 15, quad = lane >> 4;
    // XCD-aware swizzle: nwg=1024, divisible by 8 -> bijective
    const int bid = blockIdx.x;
    const int bm = ((bid & 7) * 128 + (bid >> 3)) * 64;

    if (tid < 64) tg_sh[tid] = tgtp[bm + tid];

    // ---- phase 1: gather full-K M1 rows into registers ----
    bf16x8 zt[4], zs[4];
    #pragma unroll
    for (int u = 0; u < 4; ++u) {
        int g = u * 512 + tid;           // [0, 2048): 64 rows x 32 chunks(16B)
        int r = g >> 5, c = g & 31;
        int i = bm + r;
        int tg = tgtp[i], sr = srcp[i];
        zt[u] = *reinterpret_cast<const bf16x8*>(Z + (size_t)tg * 512 + c * 8);
        zs[u] = *reinterpret_cast<const bf16x8*>(Z + (size_t)sr * 512 + 256 + c * 8);
    }
    // ---- phase 2: fuse (add + bm1 + relu), write As ----
    #pragma unroll
    for (int u = 0; u < 4; ++u) {
        int g = u * 512 + tid;
        int r = g >> 5, c = g & 31;
        PU a, b, o;
        a.v = zt[u]; b.v = zs[u];
        float4 k0v = *reinterpret_cast<const float4*>(kbias + c * 8);
        float4 k1v = *reinterpret_cast<const float4*>(kbias + c * 8 + 4);
        float bb[8] = {k0v.x, k0v.y, k0v.z, k0v.w, k1v.x, k1v.y, k1v.z, k1v.w};
        #pragma unroll
        for (int j = 0; j < 8; ++j) {
            float v = __bfloat162float(a.h[j]) + __bfloat162float(b.h[j]) + bb[j];
            o.h[j] = __float2bfloat16(fmaxf(v, 0.f));
        }
        *reinterpret_cast<bf16x8*>(&As[r * LDA + c * 8]) = o.v;
    }
    __syncthreads();

    const int wn = w;
    f32x4 acc[4][2];
    #pragma unroll
    for (int mt = 0; mt < 4; ++mt)
        #pragma unroll
        for (int nt = 0; nt < 2; ++nt)
            #pragma unroll
            for (int r = 0; r < 4; ++r) acc[mt][nt][r] = 0.f;

    #pragma unroll
    for (int k0 = 0; k0 < 256; k0 += 32) {
        bf16x8 af[4], bfr[2];
        #pragma unroll
        for (int nt = 0; nt < 2; ++nt)
            bfr[nt] = *reinterpret_cast<const bf16x8*>(
                B + (size_t)(wn * 32 + nt * 16 + l16) * 256 + k0 + quad * 8);
        #pragma unroll
        for (int mt = 0; mt < 4; ++mt)
            af[mt] = *reinterpret_cast<const bf16x8*>(&As[(mt * 16 + l16) * LDA + k0 + quad * 8]);
        #pragma unroll
        for (int mt = 0; mt < 4; ++mt)
            #pragma unroll
            for (int nt = 0; nt < 2; ++nt)
                acc[mt][nt] = __builtin_amdgcn_mfma_f32_16x16x32_bf16(af[mt], bfr[nt], acc[mt][nt], 0, 0, 0);
    }

    // ---- epilogue: relu+bias into the As tile (bf16, same rounding as the
    //      old M216 path), then per-column CSR-run segmented sum -> A3f ----
    __syncthreads();   // all waves done reading As
    #pragma unroll
    for (int mt = 0; mt < 4; ++mt) {
        #pragma unroll
        for (int nt = 0; nt < 2; ++nt) {
            int col = wn * 32 + nt * 16 + l16;
            float bv = bias[col];
            #pragma unroll
            for (int r = 0; r < 4; ++r) {
                int rl = mt * 16 + quad * 4 + r;
                As[rl * LDA + col] = __float2bfloat16(fmaxf(acc[mt][nt][r] + bv, 0.f));
            }
        }
    }
    __syncthreads();
    {
        int col = tid & 255, r0 = (tid >> 8) * 32;
        float s = 0.f;
        int cur = tg_sh[r0];
        #pragma unroll 8
        for (int r = 0; r < 32; ++r) {
            int rr = r0 + r;
            int t = tg_sh[rr];
            if (t != cur) {
                atomicAdd(&A3f[(size_t)cur * 256 + col], s);
                s = 0.f; cur = t;
            }
            s += __bfloat162float(As[rr * LDA + col]);
        }
        atomicAdd(&A3f[(size_t)cur * 256 + col], s);
    }
}

// ---------------------------------------------------------------------------
// Batched (grid.z) 64x64 GEMM slices: M=4096, N=256 (per slice), K=256, ldb=256.
// ---------------------------------------------------------------------------
struct GSet { const __hip_bfloat16* A; int lda; const __hip_bfloat16* B;
              const float* bias; const float* rowscale;
              const float* extra; float esc; float cscale;
              __hip_bfloat16* C; float* Cf; int vtout; int ldc; int coloff; };
struct GPack { GSet s[8]; };

__global__ __launch_bounds__(256) void gemm_bz(GPack p, const int* __restrict__ eidx)
{
    GSet g = p.s[blockIdx.z];
    constexpr int LDT = 40;
    __shared__ alignas(16) __hip_bfloat16 As[64 * LDT];
    __shared__ alignas(16) __hip_bfloat16 Bs[64 * LDT];

    const int tid = threadIdx.x;
    const int w = tid >> 6, lane = tid & 63, l16 = lane & 15, quad = lane >> 4;
    const int wm = w >> 1, wn = w & 1;
    const int bm = blockIdx.y * 64, bn = blockIdx.x * 64;

    f32x4 acc[2][2];
    #pragma unroll
    for (int i = 0; i < 2; ++i)
        #pragma unroll
        for (int j = 0; j < 2; ++j)
            #pragma unroll
            for (int r = 0; r < 4; ++r) acc[i][j][r] = 0.f;

    for (int k0 = 0; k0 < 256; k0 += 32) {
        #pragma unroll
        for (int f = tid; f < 256; f += 256) {
            int r = f >> 2, sg = f & 3;
            *reinterpret_cast<uint4*>(&As[r * LDT + sg * 8]) =
                *reinterpret_cast<const uint4*>(g.A + (size_t)(bm + r) * g.lda + k0 + sg * 8);
            *reinterpret_cast<uint4*>(&Bs[r * LDT + sg * 8]) =
                *reinterpret_cast<const uint4*>(g.B + (size_t)(bn + r) * 256 + k0 + sg * 8);
        }
        __syncthreads();
        bf16x8 af[2], bfr[2];
        #pragma unroll
        for (int mt = 0; mt < 2; ++mt)
            af[mt] = *reinterpret_cast<const bf16x8*>(&As[(wm * 32 + mt * 16 + l16) * LDT + quad * 8]);
        #pragma unroll
        for (int nt = 0; nt < 2; ++nt)
            bfr[nt] = *reinterpret_cast<const bf16x8*>(&Bs[(wn * 32 + nt * 16 + l16) * LDT + quad * 8]);
        #pragma unroll
        for (int mt = 0; mt < 2; ++mt)
            #pragma unroll
            for (int nt = 0; nt < 2; ++nt)
                acc[mt][nt] = __builtin_amdgcn_mfma_f32_16x16x32_bf16(af[mt], bfr[nt], acc[mt][nt], 0, 0, 0);
        __syncthreads();
    }

    #pragma unroll
    for (int mt = 0; mt < 2; ++mt) {
        #pragma unroll
        for (int nt = 0; nt < 2; ++nt) {
            int colL = bn + wn * 32 + nt * 16 + l16;
            #pragma unroll
            for (int r = 0; r < 4; ++r) {
                int row = bm + wm * 32 + mt * 16 + quad * 4 + r;
                float v = acc[mt][nt][r];
                if (g.bias) {
                    float bv = g.bias[colL];
                    if (g.rowscale) bv *= g.rowscale[row];
                    v += bv;
                }
                if (g.extra) v += g.esc * g.extra[(size_t)eidx[row] * QD + colL];
                v *= g.cscale;
                if (g.vtout)
                    g.C[(size_t)colL * 4096 + row] = __float2bfloat16(v);
                else if (g.Cf)
                    g.Cf[(size_t)row * g.ldc + g.coloff + colL] = v;
                else
                    g.C[(size_t)row * g.ldc + g.coloff + colL] = __float2bfloat16(v);
            }
        }
    }
}

// ---------------------------------------------------------------------------
// fp32 tiled composite-weight GEMM (startup): 32x32 tile, BK=16, 2x2 microtile.
// ---------------------------------------------------------------------------
struct FDesc { const float* A; int lda; const float* B; int ldb; int tb;
               const float* bias; float* C; int M, N, K; };
struct FPack { FDesc d[16]; };

__global__ __launch_bounds__(256) void fgemm2(FPack p)
{
    FDesc c = p.d[blockIdx.z];
    int bm = blockIdx.y * 32, bn = blockIdx.x * 32;
    if (bm >= c.M || bn >= c.N) return;
    __shared__ float As[16][33];
    __shared__ float Bs[16][33];
    int tid = threadIdx.x;
    int tr = tid / 16, tc = tid % 16;
    float acc[2][2] = {};

    for (int k0 = 0; k0 < c.K; k0 += 16) {
        #pragma unroll
        for (int u = 0; u < 2; ++u) {
            int i = tid * 2 + u;
            int m = i >> 4, kk = i & 15;
            int row = bm + m, kg = k0 + kk;
            As[kk][m] = (row < c.M && kg < c.K) ? c.A[(size_t)row * c.lda + kg] : 0.f;
        }
        if (c.tb) {
            #pragma unroll
            for (int u = 0; u < 2; ++u) {
                int i = tid * 2 + u;
                int n = i >> 4, kk = i & 15;
                int col = bn + n, kg = k0 + kk;
                Bs[kk][n] = (col < c.N && kg < c.K) ? c.B[(size_t)col * c.ldb + kg] : 0.f;
            }
        } else {
            #pragma unroll
            for (int u = 0; u < 2; ++u) {
                int i = tid * 2 + u;
                int kk = i >> 5, n = i & 31;
                int col = bn + n, kg = k0 + kk;
                Bs[kk][n] = (col < c.N && kg < c.K) ? c.B[(size_t)kg * c.ldb + col] : 0.f;
            }
        }
        __syncthreads();
        #pragma unroll
        for (int kk = 0; kk < 16; ++kk) {
            float a0 = As[kk][tr * 2], a1 = As[kk][tr * 2 + 1];
            float b0 = Bs[kk][tc * 2], b1 = Bs[kk][tc * 2 + 1];
            acc[0][0] = fmaf(a0, b0, acc[0][0]);
            acc[0][1] = fmaf(a0, b1, acc[0][1]);
            acc[1][0] = fmaf(a1, b0, acc[1][0]);
            acc[1][1] = fmaf(a1, b1, acc[1][1]);
        }
        __syncthreads();
    }

    #pragma unroll
    for (int i = 0; i < 2; ++i) {
        int row = bm + tr * 2 + i;
        if (row >= c.M) continue;
        #pragma unroll
        for (int j = 0; j < 2; ++j) {
            int col = bn + tc * 2 + j;
            if (col >= c.N) continue;
            float v = acc[i][j];
            if (c.bias) v += c.bias[col];
            c.C[(size_t)row * c.N + col] = v;
        }
    }
}

// ---------------------------------------------------------------------------
// Flash MHA v10b: 64 q-rows per block (4 q-sets shared by 8 key-split waves),
// 512 threads, grid (64, 8).  Ones-MFMA row-sum (denominator on the matrix
// pipe).  Harness-verified 49-50 us.  16-wave variants spilled (v11);
// key-split atomic merge regressed (v12: 68 us, 72MB atomic traffic).
// ---------------------------------------------------------------------------
__global__ __launch_bounds__(512, 4) void mha_flash10(
    const __hip_bfloat16* __restrict__ Qm,
    const __hip_bfloat16* __restrict__ Km,
    const __hip_bfloat16* __restrict__ Vt, __hip_bfloat16* __restrict__ Out)
{
    const int hh = blockIdx.y;
    const int tid = threadIdx.x;
    const int w = tid >> 6, lane = tid & 63, l16 = lane & 15, quad = lane >> 4;
    const int qb = blockIdx.x * 64;

    __shared__ float Osh[8][4][64][9];   // [9] pad: conflict-free scalar merge
    __shared__ float Lsh[8][4][16];

    bf16x8 aq[4];
    #pragma unroll
    for (int s = 0; s < 4; ++s)
        aq[s] = *reinterpret_cast<const bf16x8*>(
            Qm + (size_t)(qb + s * 16 + l16) * 256 + hh * 32 + quad * 8);
    const __hip_bfloat16* vb0 = Vt + (size_t)(hh * 32 + l16) * 4096;
    const __hip_bfloat16* vb1 = vb0 + (size_t)16 * 4096;
    const int rowoff = (l16 >> 2) * 8 + (l16 & 3);
    const f32x4 zero = {0.f, 0.f, 0.f, 0.f};

    PU onesu;
    #pragma unroll
    for (int j = 0; j < 8; ++j) onesu.h[j] = __float2bfloat16(1.f);
    const bf16x8 onesv = onesu.v;

    f32x4 o0[4], o1[4], lac[4];
    #pragma unroll
    for (int s = 0; s < 4; ++s) { o0[s] = zero; o1[s] = zero; lac[s] = zero; }

    const int kstart = w * 512;
    for (int kt = 0; kt < 8; ++kt) {
        const int kbase = kstart + kt * 64;
        bf16x8 kf[4];
        #pragma unroll
        for (int c = 0; c < 2; ++c)
            #pragma unroll
            for (int st = 0; st < 2; ++st)
                kf[c * 2 + st] = *reinterpret_cast<const bf16x8*>(
                    Km + (size_t)(kbase + c * 32 + st * 4 + rowoff) * 256 + hh * 32 + quad * 8);
        bf16x8 v00 = *reinterpret_cast<const bf16x8*>(vb0 + kbase + quad * 8);
        bf16x8 v01 = *reinterpret_cast<const bf16x8*>(vb1 + kbase + quad * 8);
        bf16x8 v10 = *reinterpret_cast<const bf16x8*>(vb0 + kbase + 32 + quad * 8);
        bf16x8 v11 = *reinterpret_cast<const bf16x8*>(vb1 + kbase + 32 + quad * 8);

        #pragma unroll
        for (int s = 0; s < 4; ++s) {
            f32x4 sv[4];
            __builtin_amdgcn_s_setprio(1);
            #pragma unroll
            for (int i = 0; i < 4; ++i)
                sv[i] = __builtin_amdgcn_mfma_f32_16x16x32_bf16(kf[i], aq[s], zero, 0, 0, 0);
            __builtin_amdgcn_s_setprio(0);
            PU p0, p1;
            #pragma unroll
            for (int i = 0; i < 4; ++i) {
                float e0 = exp2f(sv[i][0]), e1 = exp2f(sv[i][1]);
                float e2 = exp2f(sv[i][2]), e3 = exp2f(sv[i][3]);
                PU& pp = (i < 2) ? p0 : p1;
                pp.b2[(i & 1) * 2 + 0] = __float22bfloat162_rn(make_float2(e0, e1));
                pp.b2[(i & 1) * 2 + 1] = __float22bfloat162_rn(make_float2(e2, e3));
            }
            __builtin_amdgcn_s_setprio(1);
            o0[s]  = __builtin_amdgcn_mfma_f32_16x16x32_bf16(v00,   p0.v, o0[s],  0, 0, 0);
            o1[s]  = __builtin_amdgcn_mfma_f32_16x16x32_bf16(v01,   p0.v, o1[s],  0, 0, 0);
            lac[s] = __builtin_amdgcn_mfma_f32_16x16x32_bf16(onesv, p0.v, lac[s], 0, 0, 0);
            o0[s]  = __builtin_amdgcn_mfma_f32_16x16x32_bf16(v10,   p1.v, o0[s],  0, 0, 0);
            o1[s]  = __builtin_amdgcn_mfma_f32_16x16x32_bf16(v11,   p1.v, o1[s],  0, 0, 0);
            lac[s] = __builtin_amdgcn_mfma_f32_16x16x32_bf16(onesv, p1.v, lac[s], 0, 0, 0);
            __builtin_amdgcn_s_setprio(0);
        }
    }

    // lac rows are all identical (= sum over this wave's keys for q-col l16)
    float lsum[4];
    #pragma unroll
    for (int s = 0; s < 4; ++s) lsum[s] = lac[s][0];

    #pragma unroll
    for (int s = 0; s < 4; ++s) {
        #pragma unroll
        for (int r = 0; r < 4; ++r) {
            Osh[w][s][lane][r]     = o0[s][r];
            Osh[w][s][lane][4 + r] = o1[s][r];
        }
        if (quad == 0) Lsh[w][s][l16] = lsum[s];
    }
    __syncthreads();
    if (w < 4) {
        const int s = w;
        f32x4 a0 = zero, a1 = zero;
        float ll = 0.f;
        #pragma unroll
        for (int ww = 0; ww < 8; ++ww) {
            #pragma unroll
            for (int r = 0; r < 4; ++r) {
                a0[r] += Osh[ww][s][lane][r];
                a1[r] += Osh[ww][s][lane][4 + r];
            }
            ll += Lsh[ww][s][l16];
        }
        float inv = 1.f / ll;
        __hip_bfloat16* dst = Out + (size_t)(qb + s * 16 + l16) * 256 + hh * 32;
        #pragma unroll
        for (int r = 0; r < 4; ++r) {
            dst[quad * 4 + r]      = __float2bfloat16(a0[r] * inv);
            dst[16 + quad * 4 + r] = __float2bfloat16(a1[r] * inv);
        }
    }
}

// build mask bitfield + per-target degree count in one pass
__global__ __launch_bounds__(256) void build_mask(const int* __restrict__ src,
                                                  const int* __restrict__ tgt,
                                                  unsigned* __restrict__ mb,
                                                  int* __restrict__ cnt)
{
    int e = blockIdx.x * 256 + threadIdx.x;
    if (e >= E_EDGES) return;
    int t = tgt[e];
    atomicOr(mb + (size_t)src[e] * (N_NODES / 32) + (t >> 5), 1u << (t & 31));
    atomicAdd(&cnt[t], 1);
}

__global__ __launch_bounds__(1024) void csr_scan(const int* __restrict__ cnt, int* __restrict__ off,
                                                 int* __restrict__ cursor, float* __restrict__ degf)
{
    __shared__ int sh[1024];
    int t = threadIdx.x;
    int base = t * 4;
    int c0 = cnt[base], c1 = cnt[base + 1], c2 = cnt[base + 2], c3 = cnt[base + 3];
    int sum = c0 + c1 + c2 + c3;
    sh[t] = sum; __syncthreads();
    for (int d = 1; d < 1024; d <<= 1) {
        int v = (t >= d) ? sh[t - d] : 0;
        __syncthreads();
        sh[t] += v;
        __syncthreads();
    }
    int excl = sh[t] - sum;
    int o0 = excl, o1 = excl + c0, o2 = o1 + c1, o3 = o2 + c2;
    off[base] = o0; off[base + 1] = o1; off[base + 2] = o2; off[base + 3] = o3;
    cursor[base] = o0; cursor[base + 1] = o1; cursor[base + 2] = o2; cursor[base + 3] = o3;
    degf[base] = (float)c0; degf[base + 1] = (float)c1;
    degf[base + 2] = (float)c2; degf[base + 3] = (float)c3;
    if (t == 1023) off[4096] = sh[t];
}

__global__ __launch_bounds__(256) void csr_fill(const int* __restrict__ src, const int* __restrict__ tgt,
                                                int* __restrict__ cursor,
                                                int* __restrict__ srcp, int* __restrict__ tgtp)
{
    int e = blockIdx.x * 256 + threadIdx.x;
    if (e >= E_EDGES) return;
    int t = tgt[e];
    int pos = atomicAdd(&cursor[t], 1);
    srcp[pos] = src[e];
    tgtp[pos] = t;
}

// Sparse graph-masked attention over bf16 Q,K,V. Writes out (=).
__global__ __launch_bounds__(256) void sparse_attn(
    const __hip_bfloat16* __restrict__ Q, const __hip_bfloat16* __restrict__ K,
    const __hip_bfloat16* __restrict__ V, int vld,
    const unsigned* __restrict__ maskb, float* __restrict__ outb)
{
    int i = blockIdx.x, t = threadIdx.x;
    __shared__ float qsh[256];
    __shared__ int   nb[1024];
    __shared__ float sc[1024];
    __shared__ int   cnt;
    __shared__ float red[4];
    __shared__ float smax, ssum;
    if (t == 0) cnt = 0;
    qsh[t] = __bfloat162float(Q[(size_t)i * 256 + t]);
    __syncthreads();
    if (t < 128) {
        unsigned wv = maskb[(size_t)i * 128 + t];
        while (wv) {
            int b = __ffs(wv) - 1; wv &= wv - 1;
            int p = atomicAdd(&cnt, 1);
            nb[p] = t * 32 + b;
        }
    }
    __syncthreads();
    int deg = cnt;
    int wid = t >> 6, lane = t & 63;
    if (deg > 0) {
        for (int n = wid; n < deg; n += 4) {
            union { uint2 u; __hip_bfloat16 h[4]; } kv;
            kv.u = *reinterpret_cast<const uint2*>(K + (size_t)nb[n] * 256 + lane * 4);
            float s = qsh[lane*4+0] * __bfloat162float(kv.h[0]) + qsh[lane*4+1] * __bfloat162float(kv.h[1])
                    + qsh[lane*4+2] * __bfloat162float(kv.h[2]) + qsh[lane*4+3] * __bfloat162float(kv.h[3]);
            #pragma unroll
            for (int off = 32; off; off >>= 1) s += __shfl_xor(s, off);
            if (lane == 0) sc[n] = s * 0.0625f;
        }
        __syncthreads();
        float m = -3.4e38f;
        for (int n = t; n < deg; n += 256) m = fmaxf(m, sc[n]);
        #pragma unroll
        for (int off = 32; off; off >>= 1) m = fmaxf(m, __shfl_xor(m, off));
        if (lane == 0) red[wid] = m;
        __syncthreads();
        if (t == 0) smax = fmaxf(fmaxf(red[0], red[1]), fmaxf(red[2], red[3]));
        __syncthreads();
        float ls = 0.f;
        for (int n = t; n < deg; n += 256) { float e = __expf(sc[n] - smax); sc[n] = e; ls += e; }
        #pragma unroll
        for (int off = 32; off; off >>= 1) ls += __shfl_xor(ls, off);
        if (lane == 0) red[wid] = ls;
        __syncthreads();
        if (t == 0) ssum = red[0] + red[1] + red[2] + red[3];
        __syncthreads();
        float inv = 1.f / ssum;
        float o = 0.f;
        for (int n = 0; n < deg; ++n)
            o += sc[n] * __bfloat162float(V[(size_t)nb[n] * vld + t]);
        outb[(size_t)i * 256 + t] = o * inv;
    } else {
        float o = 0.f;
        for (int j = 0; j < N_NODES; ++j) o += __bfloat162float(V[(size_t)j * vld + t]);
        outb[(size_t)i * 256 + t] = o * (1.f / N_NODES);
    }
}

// h = LN(h + a1 + a2 + a3)
__global__ __launch_bounds__(256) void ln_kernel(float* __restrict__ h, __hip_bfloat16* __restrict__ h16,
                                                 const float* __restrict__ a1,
                                                 const float* __restrict__ a2,
                                                 const float* __restrict__ a3,
                                                 const float* __restrict__ g, const float* __restrict__ b)
{
    int row = blockIdx.x, t = threadIdx.x;
    __shared__ float red[256];
    size_t off = ((size_t)row << 8) + t;
    float v = h[off] + a1[off] + a2[off] + a3[off];
    red[t] = v; __syncthreads();
    for (int s = 128; s > 0; s >>= 1) { if (t < s) red[t] += red[t + s]; __syncthreads(); }
    float mu = red[0] * (1.f / 256.f); __syncthreads();
    float d = v - mu;
    red[t] = d * d; __syncthreads();
    for (int s = 128; s > 0; s >>= 1) { if (t < s) red[t] += red[t + s]; __syncthreads(); }
    float var = red[0] * (1.f / 256.f);
    float r = d * rsqrtf(var + 1e-5f) * g[t] + b[t];
    h[off] = r;
    h16[off] = __float2bfloat16(r);
}

__global__ __launch_bounds__(256) void colpool(const float* __restrict__ h, float* __restrict__ p)
{
    int c = blockIdx.x, t = threadIdx.x;
    __shared__ float rs[256], rm[256];
    float s = 0.f, m = -3.4e38f;
    for (int row = t; row < N_NODES; row += 256) {
        float v = h[((size_t)row << 8) + c];
        s += v; m = fmaxf(m, v);
    }
    rs[t] = s; rm[t] = m; __syncthreads();
    for (int st = 128; st > 0; st >>= 1) {
        if (t < st) { rs[t] += rs[t + st]; rm[t] = fmaxf(rm[t], rm[t + st]); }
        __syncthreads();
    }
    if (t == 0) { p[c] = rs[0] * (1.f / N_NODES); p[256 + c] = rm[0]; }
}

__global__ __launch_bounds__(256) void classifier(const float* __restrict__ pooled,
                                                  const float* __restrict__ Wc1, const float* __restrict__ bc1,
                                                  const float* __restrict__ Wc2, const float* __restrict__ bc2,
                                                  float* __restrict__ out)
{
    __shared__ float p[512];
    __shared__ float z[256];
    int t = threadIdx.x;
    p[t] = pooled[t]; p[256 + t] = pooled[256 + t];
    __syncthreads();
    float s = bc1[t];
    for (int k = 0; k < 512; ++k) s = fmaf(p[k], Wc1[k * 256 + t], s);
    z[t] = fmaxf(s, 0.f);
    __syncthreads();
    if (t < OUT_F) {
        float o = bc2[t];
        for (int j = 0; j < 256; ++j) o = fmaf(z[j], Wc2[j * OUT_F + t], o);
        out[t] = o;
    }
}

// ---- bf16 conversion ----
struct CDesc { const float* s; __hip_bfloat16* d; int total; };
struct CPack { CDesc d[2]; };
__global__ __launch_bounds__(256) void convert_copy(CPack p)
{
    CDesc c = p.d[blockIdx.y];
    for (int i = blockIdx.x * 256 + threadIdx.x; i < c.total; i += gridDim.x * 256)
        c.d[i] = __float2bfloat16(c.s[i]);
}
// LDS-tiled transpose-convert: d[n*K+k] = bf16(s[k*sld+n]); coalesced both sides
struct TDesc { const float* s; __hip_bfloat16* d; int K, N, sld; };
struct TPack { TDesc d[23]; };
__global__ __launch_bounds__(256) void convert_t32(TPack p)
{
    TDesc c = p.d[blockIdx.z];
    int k0 = blockIdx.x * 32, n0 = blockIdx.y * 32;
    if (k0 >= c.K || n0 >= c.N) return;
    __shared__ float t[32][33];
    int tr = threadIdx.x >> 5, tc = threadIdx.x & 31;
    #pragma unroll
    for (int rr = 0; rr < 32; rr += 8)
        t[tc][tr + rr] = c.s[(size_t)(k0 + tr + rr) * c.sld + n0 + tc];
    __syncthreads();
    #pragma unroll
    for (int rr = 0; rr < 32; rr += 8)
        c.d[(size_t)(n0 + tr + rr) * c.K + k0 + tc] = __float2bfloat16(t[tr + rr][tc]);
}

extern "C" void kernel_launch(void* const* d_in, const int* in_sizes, int n_in,
                              void* d_out, int out_size, void* d_ws, size_t ws_size,
                              hipStream_t stream)
{
    const float* x    = (const float*)d_in[0];
    const int*   ei   = (const int*)d_in[1];
    const int*   ct   = (const int*)d_in[2];
    const float* Wi   = (const float*)d_in[3];
    const float* bi   = (const float*)d_in[4];
    const float* Wq   = (const float*)d_in[5];
    const float* bq   = (const float*)d_in[6];
    const float* Wk   = (const float*)d_in[7];
    const float* bk   = (const float*)d_in[8];
    const float* Wv   = (const float*)d_in[9];
    const float* bv   = (const float*)d_in[10];
    const float* Bc   = (const float*)d_in[11];
    const float* cemb = (const float*)d_in[12];
    const float* Win  = (const float*)d_in[13];
    const float* binp = (const float*)d_in[14];
    const float* Wo   = (const float*)d_in[15];
    const float* bo   = (const float*)d_in[16];
    const float* Wm1  = (const float*)d_in[17];
    const float* bm1  = (const float*)d_in[18];
    const float* Wm2  = (const float*)d_in[19];
    const float* bm2  = (const float*)d_in[20];
    const float* Wm3  = (const float*)d_in[21];
    const float* bm3  = (const float*)d_in[22];
    const float* lng  = (const float*)d_in[23];
    const float* lnb  = (const float*)d_in[24];
    const float* Wc1  = (const float*)d_in[25];
    const float* bc1  = (const float*)d_in[26];
    const float* Wc2  = (const float*)d_in[27];
    const float* bc2  = (const float*)d_in[28];

    const int* src = ei;
    const int* tgt = ei + E_EDGES;

    // ---- workspace carve-up ----
    char* wp = (char*)d_ws;
    auto alloc = [&](size_t bytes) { char* r = wp; wp += (bytes + 255) & ~(size_t)255; return r; };
    const size_t NH = (size_t)N_NODES * 256;
    float* h      = (float*)alloc(NH * 4);
    float* a1     = (float*)alloc(NH * 4);
    float* a2     = (float*)alloc(NH * 4);
    float* a3     = (float*)alloc(NH * 4);
    float* pooled = (float*)alloc(512 * 4);
    float* degf   = (float*)alloc(N_NODES * 4);
    float* A3f    = (float*)alloc(NH * 4);   // fused edge seg-sum accumulator
    __hip_bfloat16* x16 = (__hip_bfloat16*)alloc((size_t)N_NODES * 512 * 2);
    __hip_bfloat16* h16 = (__hip_bfloat16*)alloc(NH * 2);
    __hip_bfloat16* Qb  = (__hip_bfloat16*)alloc(NH * 2);
    __hip_bfloat16* Kb  = (__hip_bfloat16*)alloc(NH * 2);
    __hip_bfloat16* Vb  = (__hip_bfloat16*)alloc(NH * 2);
    __hip_bfloat16* Tq  = (__hip_bfloat16*)alloc(NH * 2);
    __hip_bfloat16* Tk  = (__hip_bfloat16*)alloc(NH * 2);
    __hip_bfloat16* Vt  = (__hip_bfloat16*)alloc(NH * 2);
    __hip_bfloat16* Z12 = (__hip_bfloat16*)alloc((size_t)N_NODES * 512 * 2);
    __hip_bfloat16* A3  = (__hip_bfloat16*)alloc(NH * 2);
    __hip_bfloat16* Wi_t= (__hip_bfloat16*)alloc((size_t)256 * 512 * 2);
    // fp32 composite weights / biases / ce-tables, per layer
    float *Wqc_f[2], *Wkc_f[2], *Wqm_f[2], *Wkm_f[2], *Wvm_f[2];
    float *bqc[2], *bkc[2], *bqm[2], *bkm[2], *bvm[2], *ceq2[2], *cek2[2];
    for (int l = 0; l < 2; ++l) {
        Wqc_f[l] = (float*)alloc(65536 * 4); Wkc_f[l] = (float*)alloc(65536 * 4);
        Wqm_f[l] = (float*)alloc(65536 * 4); Wkm_f[l] = (float*)alloc(65536 * 4);
        Wvm_f[l] = (float*)alloc(65536 * 4);
        bqc[l] = (float*)alloc(256 * 4); bkc[l] = (float*)alloc(256 * 4);
        bqm[l] = (float*)alloc(256 * 4); bkm[l] = (float*)alloc(256 * 4);
        bvm[l] = (float*)alloc(256 * 4);
        ceq2[l] = (float*)alloc(CT_N * 256 * 4); cek2[l] = (float*)alloc(CT_N * 256 * 4);
    }
    // bf16 [N][K] weights: per layer: Wqc,Wkc,Wqm,Wkm,Wvm,Wv,Wo,Wm1a,Wm1b,Wm2,Wm3
    __hip_bfloat16* WB[2][11];
    for (int l = 0; l < 2; ++l)
        for (int m = 0; m < 11; ++m)
            WB[l][m] = (__hip_bfloat16*)alloc(65536 * 2);
    unsigned* maskb = (unsigned*)alloc((size_t)N_NODES * 128 * 4);
    int* cnt    = (int*)alloc(N_NODES * 4);
    int* cursor = (int*)alloc(N_NODES * 4);
    int* off    = (int*)alloc((N_NODES + 1) * 4);
    int* srcp   = (int*)alloc(E_EDGES * 4);
    int* tgtp   = (int*)alloc(E_EDGES * 4);

    // ---- startup: x conversion ----
    CPack cp; cp.d[0] = {x, x16, N_NODES * 512};
    convert_copy<<<dim3(256, 1), 256, 0, stream>>>(cp);

    // ---- composite fp32 weights (tiled fgemm2, 2 dependent waves) ----
    FPack f1; int n1 = 0;
    FPack f2; int n2 = 0;
    for (int l = 0; l < 2; ++l) {
        const float* Wq_l  = Wq + (size_t)l * 65536;
        const float* Wk_l  = Wk + (size_t)l * 65536;
        const float* Wv_l  = Wv + (size_t)l * 65536;
        const float* Bc_l  = Bc + (size_t)l * 65536;
        const float* Win_l = Win + (size_t)l * 256 * 768;
        const float* ce_l  = cemb + (size_t)l * CT_N * QD;
        const float* bq_l  = bq + l * 256;
        const float* bk_l  = bk + l * 256;
        const float* bv_l  = bv + l * 256;
        const float* bin_l = binp + l * 768;
        f1.d[n1++] = {Wq_l, 256, Bc_l, 256, 0, nullptr, Wqc_f[l], 256, 256, 256};
        f1.d[n1++] = {Wk_l, 256, Bc_l, 256, 1, nullptr, Wkc_f[l], 256, 256, 256};
        f1.d[n1++] = {bq_l, 256, Bc_l, 256, 0, nullptr, bqc[l], 1, 256, 256};
        f1.d[n1++] = {bk_l, 256, Bc_l, 256, 1, nullptr, bkc[l], 1, 256, 256};
        f2.d[n2++] = {Wqc_f[l], 256, Win_l,       768, 0, nullptr, Wqm_f[l], 256, 256, 256};
        f2.d[n2++] = {Wkc_f[l], 256, Win_l + 256, 768, 0, nullptr, Wkm_f[l], 256, 256, 256};
        f2.d[n2++] = {Wv_l,     256, Win_l + 512, 768, 0, nullptr, Wvm_f[l], 256, 256, 256};
        f2.d[n2++] = {ce_l,     256, Win_l,       768, 0, nullptr, ceq2[l], CT_N, 256, 256};
        f2.d[n2++] = {ce_l,     256, Win_l + 256, 768, 0, nullptr, cek2[l], CT_N, 256, 256};
        f2.d[n2++] = {bqc[l],   256, Win_l,       768, 0, bin_l,       bqm[l], 1, 256, 256};
        f2.d[n2++] = {bkc[l],   256, Win_l + 256, 768, 0, bin_l + 256, bkm[l], 1, 256, 256};
        f2.d[n2++] = {bv_l,     256, Win_l + 512, 768, 0, bin_l + 512, bvm[l], 1, 256, 256};
    }
    fgemm2<<<dim3(8, 8, n1), 256, 0, stream>>>(f1);
    fgemm2<<<dim3(8, 8, n2), 256, 0, stream>>>(f2);

    // ---- transpose-convert all [K][N] fp32 weights to bf16 [N][K] ----
    TPack tp; int ndt = 0;
    auto addT = [&](const float* s, __hip_bfloat16* d, int K, int N, int sld) { tp.d[ndt++] = {s, d, K, N, sld}; };
    addT(Wi, Wi_t, 512, 256, 256);
    for (int l = 0; l < 2; ++l) {
        const float* Wv_l  = Wv + (size_t)l * 65536;
        const float* Wo_l  = Wo + (size_t)l * 65536;
        const float* Wm1_l = Wm1 + (size_t)l * (2 * H_F + QD) * QD;  // layer stride 768*256!
        const float* Wm2_l = Wm2 + (size_t)l * 65536;
        const float* Wm3_l = Wm3 + (size_t)l * 65536;
        addT(Wqc_f[l], WB[l][0], 256, 256, 256);
        addT(Wkc_f[l], WB[l][1], 256, 256, 256);
        addT(Wqm_f[l], WB[l][2], 256, 256, 256);
        addT(Wkm_f[l], WB[l][3], 256, 256, 256);
        addT(Wvm_f[l], WB[l][4], 256, 256, 256);
        addT(Wv_l,     WB[l][5], 256, 256, 256);
        addT(Wo_l,     WB[l][6], 256, 256, 256);
        addT(Wm1_l,             WB[l][7], 256, 256, 256);
        addT(Wm1_l + 256 * 256, WB[l][8], 256, 256, 256);
        addT(Wm2_l,    WB[l][9],  256, 256, 256);
        addT(Wm3_l,    WB[l][10], 256, 256, 256);
    }
    convert_t32<<<dim3(16, 8, ndt), 256, 0, stream>>>(tp);

    hipMemsetAsync(maskb, 0, (size_t)N_NODES * 128 * 4, stream);
    hipMemsetAsync(cnt, 0, N_NODES * 4, stream);
    build_mask<<<E_EDGES / 256, 256, 0, stream>>>(src, tgt, maskb, cnt);
    csr_scan<<<1, 1024, 0, stream>>>(cnt, off, cursor, degf);
    csr_fill<<<E_EDGES / 256, 256, 0, stream>>>(src, tgt, cursor, srcp, tgtp);

    // h = relu(x @ Wi + bi)
    gemm_mfma<64, 64, false><<<dim3(4, 64), 256, 0, stream>>>(
        x16, 512, Wi_t, 512, h, h16, 256, 512,
        bi, nullptr, nullptr, nullptr, nullptr, FLAG_RELU | FLAG_WF32 | FLAG_WB16);

    const float QSCALE = 0.25507693f;   // log2(e)/sqrt(32)

    for (int l = 0; l < L_LAYERS; ++l) {
        const float* ce_l  = cemb + (size_t)l * CT_N * QD;
        const float* bo_l  = bo + l * QD;
        const float* bm1_l = bm1 + l * QD;
        const float* bm2_l = bm2 + l * QD;
        const float* bm3_l = bm3 + l * H_F;
        const float* lng_l = lng + l * H_F;
        const float* lnb_l = lnb + l * H_F;
        const float* bv_l  = bv + l * 256;

        // ---- one z=8 projection launch from h ----
        {
            GPack gp;
            gp.s[0] = {h16, 256, WB[l][0], bqc[l], nullptr, ce_l,    0.1f, 1.0f,   Qb,  nullptr, 0, 256, 0};
            gp.s[1] = {h16, 256, WB[l][1], bkc[l], nullptr, ce_l,    0.1f, 1.0f,   Kb,  nullptr, 0, 256, 0};
            gp.s[2] = {h16, 256, WB[l][5], bv_l,   nullptr, nullptr, 0.f,  1.0f,   Vb,  nullptr, 0, 256, 0};
            gp.s[3] = {h16, 256, WB[l][2], bqm[l], nullptr, ceq2[l], 0.1f, QSCALE, Tq,  nullptr, 0, 256, 0};
            gp.s[4] = {h16, 256, WB[l][3], bkm[l], nullptr, cek2[l], 0.1f, 1.0f,   Tk,  nullptr, 0, 256, 0};
            gp.s[5] = {h16, 256, WB[l][4], bvm[l], nullptr, nullptr, 0.f,  1.0f,   Vt,  nullptr, 1, 256, 0};
            gp.s[6] = {h16, 256, WB[l][7], nullptr, nullptr, nullptr, 0.f, 1.0f,   Z12, nullptr, 0, 512, 0};
            gp.s[7] = {h16, 256, WB[l][8], nullptr, nullptr, nullptr, 0.f, 1.0f,   Z12, nullptr, 0, 512, 256};
            gemm_bz<<<dim3(4, 64, 8), 256, 0, stream>>>(gp, ct);
        }

        // zero the fused seg-sum accumulator (4MB, <1us)
        hipMemsetAsync(A3f, 0, NH * 4, stream);

        // sparse graph-masked attention -> a1
        sparse_attn<<<N_NODES, 256, 0, stream>>>(Qb, Kb, Vb, 256, maskb, a1);

        // flash MHA v10b (64 q-rows/block, 8 waves, ones-MFMA row-sum): heads -> Qb
        mha_flash10<<<dim3(64, NHEAD), 512, 0, stream>>>(Tq, Tk, Vt, Qb);

        // edge MLP fused with segment-sum -> A3f (fp32), then convert -> A3 bf16
        edge_gemm<<<E_EDGES / 64, 512, 0, stream>>>(
            Z12, WB[l][9], A3f, tgtp, srcp, bm1_l, bm2_l);
        {
            CPack c2; c2.d[0] = {A3f, A3, (int)NH};
            convert_copy<<<dim3(256, 1), 256, 0, stream>>>(c2);
        }

        // batched fp32 outputs: a2 = heads@Wo + bo ; a3 = A3@Wm3 + deg*bm3
        {
            GPack gp;
            gp.s[0] = {Qb, 256, WB[l][6],  bo_l,  nullptr, nullptr, 0.f, 1.0f, nullptr, a2, 0, 256, 0};
            gp.s[1] = {A3, 256, WB[l][10], bm3_l, degf,    nullptr, 0.f, 1.0f, nullptr, a3, 0, 256, 0};
            gemm_bz<<<dim3(4, 64, 2), 256, 0, stream>>>(gp, ct);
        }

        // h = LN(h + a1 + a2 + a3)
        ln_kernel<<<N_NODES, 256, 0, stream>>>(h, h16, a1, a2, a3, lng_l, lnb_l);
    }

    colpool<<<H_F, 256, 0, stream>>>(h, pooled);
    classifier<<<1, 256, 0, stream>>>(pooled, Wc1, bc1, Wc2, bc2, (float*)d_out);
}

// Round 9
// 493.928 us; speedup vs baseline: 1.1484x; 1.0125x over previous
//
#include <hip/hip_runtime.h>
#include <hip/hip_bf16.h>

#define N_NODES 4096
#define E_EDGES 65536
#define IN_F    512
#define H_F     256
#define QD      256
#define NHEAD   8
#define HD      32
#define OUT_F   10
#define L_LAYERS 2
#define CT_N    50

enum { FLAG_RELU = 1, FLAG_ACCUM = 2, FLAG_WF32 = 4, FLAG_WB16 = 8 };

typedef __attribute__((ext_vector_type(8))) __bf16 bf16x8;
typedef __attribute__((ext_vector_type(4))) float f32x4;

union PU { bf16x8 v; __hip_bfloat16 h[8]; __hip_bfloat162 b2[4]; };

// ---------------------------------------------------------------------------
// bf16 MFMA GEMM.  A: bf16 [M][K] row-major (lda).  B: bf16 [N][K] (B^T layout).
// ---------------------------------------------------------------------------
template<int BM, int BN, bool EDGE>
__global__ __launch_bounds__(256) void gemm_mfma(
    const __hip_bfloat16* __restrict__ A, int lda,
    const __hip_bfloat16* __restrict__ B, int ldb,
    float* __restrict__ Cf, __hip_bfloat16* __restrict__ Cb, int ldc,
    int K,
    const float* __restrict__ bias, const float* __restrict__ rowscale,
    const int* __restrict__ tgtp, const int* __restrict__ srcp,
    const float* __restrict__ kbias,
    int flags)
{
    constexpr int WM = BM / 2, WN = BN / 2, MT = WM / 16, NT = WN / 16;
    constexpr int LDT = 40;   // 80B row stride -> max 2-way bank alias (free, m136)
    __shared__ alignas(16) __hip_bfloat16 As[BM * LDT];
    __shared__ alignas(16) __hip_bfloat16 Bs[BN * LDT];

    const int tid = threadIdx.x;
    const int w = tid >> 6, lane = tid & 63, l16 = lane & 15, quad = lane >> 4;
    const int wm = w >> 1, wn = w & 1;
    const int bm = blockIdx.y * BM, bn = blockIdx.x * BN;

    f32x4 acc[MT][NT];
    #pragma unroll
    for (int i = 0; i < MT; ++i)
        #pragma unroll
        for (int j = 0; j < NT; ++j)
            #pragma unroll
            for (int r = 0; r < 4; ++r) acc[i][j][r] = 0.f;

    for (int k0 = 0; k0 < K; k0 += 32) {
        #pragma unroll
        for (int f = tid; f < BM * 4; f += 256) {
            int r = f >> 2, sg = f & 3;
            if (EDGE) {
                int i = bm + r;
                int tg = tgtp[i], sr = srcp[i];
                PU z1, z2, o;
                z1.v = *reinterpret_cast<const bf16x8*>(A + (size_t)tg * 512 + k0 + sg * 8);
                z2.v = *reinterpret_cast<const bf16x8*>(A + (size_t)sr * 512 + 256 + k0 + sg * 8);
                float4 b0 = *reinterpret_cast<const float4*>(kbias + k0 + sg * 8);
                float4 b1 = *reinterpret_cast<const float4*>(kbias + k0 + sg * 8 + 4);
                float bb[8] = {b0.x, b0.y, b0.z, b0.w, b1.x, b1.y, b1.z, b1.w};
                #pragma unroll
                for (int j = 0; j < 8; ++j) {
                    float v = __bfloat162float(z1.h[j]) + __bfloat162float(z2.h[j]) + bb[j];
                    o.h[j] = __float2bfloat16(fmaxf(v, 0.f));
                }
                *reinterpret_cast<bf16x8*>(&As[r * LDT + sg * 8]) = o.v;
            } else {
                *reinterpret_cast<uint4*>(&As[r * LDT + sg * 8]) =
                    *reinterpret_cast<const uint4*>(A + (size_t)(bm + r) * lda + k0 + sg * 8);
            }
        }
        #pragma unroll
        for (int f = tid; f < BN * 4; f += 256) {
            int r = f >> 2, sg = f & 3;
            *reinterpret_cast<uint4*>(&Bs[r * LDT + sg * 8]) =
                *reinterpret_cast<const uint4*>(B + (size_t)(bn + r) * ldb + k0 + sg * 8);
        }
        __syncthreads();
        bf16x8 af[MT], bfr[NT];
        #pragma unroll
        for (int mt = 0; mt < MT; ++mt)
            af[mt] = *reinterpret_cast<const bf16x8*>(&As[(wm * WM + mt * 16 + l16) * LDT + quad * 8]);
        #pragma unroll
        for (int nt = 0; nt < NT; ++nt)
            bfr[nt] = *reinterpret_cast<const bf16x8*>(&Bs[(wn * WN + nt * 16 + l16) * LDT + quad * 8]);
        #pragma unroll
        for (int mt = 0; mt < MT; ++mt)
            #pragma unroll
            for (int nt = 0; nt < NT; ++nt)
                acc[mt][nt] = __builtin_amdgcn_mfma_f32_16x16x32_bf16(af[mt], bfr[nt], acc[mt][nt], 0, 0, 0);
        __syncthreads();
    }

    #pragma unroll
    for (int mt = 0; mt < MT; ++mt) {
        #pragma unroll
        for (int nt = 0; nt < NT; ++nt) {
            int col = bn + wn * WN + nt * 16 + l16;
            #pragma unroll
            for (int r = 0; r < 4; ++r) {
                int row = bm + wm * WM + mt * 16 + quad * 4 + r;
                float v = acc[mt][nt][r];
                if (bias) {
                    float bv = bias[col];
                    if (rowscale) bv *= rowscale[row];
                    v += bv;
                }
                if (flags & FLAG_RELU) v = fmaxf(v, 0.f);
                size_t off = (size_t)row * ldc + col;
                if (flags & FLAG_ACCUM)     Cf[off] += v;
                else if (flags & FLAG_WF32) Cf[off] = v;
                if (flags & FLAG_WB16)      Cb[off] = __float2bfloat16(v);
            }
        }
    }
}

// ---------------------------------------------------------------------------
// Fused MHA + edge-MLP kernel.  blockIdx.x < 512: flash-MHA branch (v10b body,
// 2-stage LDS merge from v12 -> 37.9KB); else: edge-GEMM+seg-sum branch (v3,
// 34KB).  Union'd LDS 37.9KB -> 4 blocks/CU; mha and edge blocks co-resident,
// so edge's gather/MFMA work fills mha's idle issue slots (mha was
// latency-bound at 2 blocks/CU grid-limited: 70% idle issue).
// ---------------------------------------------------------------------------
__global__ __launch_bounds__(512, 4) void mha_edge_fused(
    const __hip_bfloat16* __restrict__ Qm,
    const __hip_bfloat16* __restrict__ Km,
    const __hip_bfloat16* __restrict__ Vt,
    __hip_bfloat16* __restrict__ Out,
    const __hip_bfloat16* __restrict__ Z,    // Z12 [N][512]
    const __hip_bfloat16* __restrict__ Bw,   // Wm2^T [256][256]
    float* __restrict__ A3f,                 // [N][256] fp32 (zeroed)
    const int* __restrict__ tgtp, const int* __restrict__ srcp,
    const float* __restrict__ kbias,         // bm1
    const float* __restrict__ bias)          // bm2
{
    constexpr int LDA = 264;
    __shared__ union SM {
        struct { float Osh[4][4][64][9]; float Lsh[4][4][16]; } m;   // 37,888 B
        struct { alignas(16) __hip_bfloat16 As[64 * LDA]; int tg[64]; } e; // 34,048 B
    } sm;

    const int tid = threadIdx.x;
    const int w = tid >> 6, lane = tid & 63, l16 = lane & 15, quad = lane >> 4;

    if (blockIdx.x < 512) {
        // ================= MHA branch =================
        const int hh = blockIdx.x >> 6;
        const int qb = (blockIdx.x & 63) * 64;

        bf16x8 aq[4];
        #pragma unroll
        for (int s = 0; s < 4; ++s)
            aq[s] = *reinterpret_cast<const bf16x8*>(
                Qm + (size_t)(qb + s * 16 + l16) * 256 + hh * 32 + quad * 8);
        const __hip_bfloat16* vb0 = Vt + (size_t)(hh * 32 + l16) * 4096;
        const __hip_bfloat16* vb1 = vb0 + (size_t)16 * 4096;
        const int rowoff = (l16 >> 2) * 8 + (l16 & 3);
        const f32x4 zero = {0.f, 0.f, 0.f, 0.f};

        PU onesu;
        #pragma unroll
        for (int j = 0; j < 8; ++j) onesu.h[j] = __float2bfloat16(1.f);
        const bf16x8 onesv = onesu.v;

        f32x4 o0[4], o1[4], lac[4];
        #pragma unroll
        for (int s = 0; s < 4; ++s) { o0[s] = zero; o1[s] = zero; lac[s] = zero; }

        const int kstart = w * 512;
        for (int kt = 0; kt < 8; ++kt) {
            const int kbase = kstart + kt * 64;
            bf16x8 kf[4];
            #pragma unroll
            for (int c = 0; c < 2; ++c)
                #pragma unroll
                for (int st = 0; st < 2; ++st)
                    kf[c * 2 + st] = *reinterpret_cast<const bf16x8*>(
                        Km + (size_t)(kbase + c * 32 + st * 4 + rowoff) * 256 + hh * 32 + quad * 8);
            bf16x8 v00 = *reinterpret_cast<const bf16x8*>(vb0 + kbase + quad * 8);
            bf16x8 v01 = *reinterpret_cast<const bf16x8*>(vb1 + kbase + quad * 8);
            bf16x8 v10 = *reinterpret_cast<const bf16x8*>(vb0 + kbase + 32 + quad * 8);
            bf16x8 v11 = *reinterpret_cast<const bf16x8*>(vb1 + kbase + 32 + quad * 8);

            #pragma unroll
            for (int s = 0; s < 4; ++s) {
                f32x4 sv[4];
                __builtin_amdgcn_s_setprio(1);
                #pragma unroll
                for (int i = 0; i < 4; ++i)
                    sv[i] = __builtin_amdgcn_mfma_f32_16x16x32_bf16(kf[i], aq[s], zero, 0, 0, 0);
                __builtin_amdgcn_s_setprio(0);
                PU p0, p1;
                #pragma unroll
                for (int i = 0; i < 4; ++i) {
                    float e0 = exp2f(sv[i][0]), e1 = exp2f(sv[i][1]);
                    float e2 = exp2f(sv[i][2]), e3 = exp2f(sv[i][3]);
                    PU& pp = (i < 2) ? p0 : p1;
                    pp.b2[(i & 1) * 2 + 0] = __float22bfloat162_rn(make_float2(e0, e1));
                    pp.b2[(i & 1) * 2 + 1] = __float22bfloat162_rn(make_float2(e2, e3));
                }
                __builtin_amdgcn_s_setprio(1);
                o0[s]  = __builtin_amdgcn_mfma_f32_16x16x32_bf16(v00,   p0.v, o0[s],  0, 0, 0);
                o1[s]  = __builtin_amdgcn_mfma_f32_16x16x32_bf16(v01,   p0.v, o1[s],  0, 0, 0);
                lac[s] = __builtin_amdgcn_mfma_f32_16x16x32_bf16(onesv, p0.v, lac[s], 0, 0, 0);
                o0[s]  = __builtin_amdgcn_mfma_f32_16x16x32_bf16(v10,   p1.v, o0[s],  0, 0, 0);
                o1[s]  = __builtin_amdgcn_mfma_f32_16x16x32_bf16(v11,   p1.v, o1[s],  0, 0, 0);
                lac[s] = __builtin_amdgcn_mfma_f32_16x16x32_bf16(onesv, p1.v, lac[s], 0, 0, 0);
                __builtin_amdgcn_s_setprio(0);
            }
        }

        float lsum[4];
        #pragma unroll
        for (int s = 0; s < 4; ++s) lsum[s] = lac[s][0];

        // ---- stage A: 8 -> 4 ----
        if (w >= 4) {
            #pragma unroll
            for (int s = 0; s < 4; ++s) {
                #pragma unroll
                for (int r = 0; r < 4; ++r) {
                    sm.m.Osh[w - 4][s][lane][r]     = o0[s][r];
                    sm.m.Osh[w - 4][s][lane][4 + r] = o1[s][r];
                }
                if (quad == 0) sm.m.Lsh[w - 4][s][l16] = lsum[s];
            }
        }
        __syncthreads();
        if (w < 4) {
            #pragma unroll
            for (int s = 0; s < 4; ++s) {
                #pragma unroll
                for (int r = 0; r < 4; ++r) {
                    o0[s][r] += sm.m.Osh[w][s][lane][r];
                    o1[s][r] += sm.m.Osh[w][s][lane][4 + r];
                }
                lsum[s] += sm.m.Lsh[w][s][l16];
            }
        }
        __syncthreads();
        // ---- stage B: distributed exchange, wave j finalizes set j ----
        if (w < 4) {
            #pragma unroll
            for (int s = 0; s < 4; ++s) {
                if (s == w) continue;
                #pragma unroll
                for (int r = 0; r < 4; ++r) {
                    sm.m.Osh[w][s][lane][r]     = o0[s][r];
                    sm.m.Osh[w][s][lane][4 + r] = o1[s][r];
                }
                if (quad == 0) sm.m.Lsh[w][s][l16] = lsum[s];
            }
        }
        __syncthreads();
        if (w < 4) {
            const int s = w;
            f32x4 a0 = o0[s], a1 = o1[s];
            float ll = lsum[s];
            #pragma unroll
            for (int i = 0; i < 4; ++i) {
                if (i == s) continue;
                #pragma unroll
                for (int r = 0; r < 4; ++r) {
                    a0[r] += sm.m.Osh[i][s][lane][r];
                    a1[r] += sm.m.Osh[i][s][lane][4 + r];
                }
                ll += sm.m.Lsh[i][s][l16];
            }
            float inv = 1.f / ll;
            __hip_bfloat16* dst = Out + (size_t)(qb + s * 16 + l16) * 256 + hh * 32;
            #pragma unroll
            for (int r = 0; r < 4; ++r) {
                dst[quad * 4 + r]      = __float2bfloat16(a0[r] * inv);
                dst[16 + quad * 4 + r] = __float2bfloat16(a1[r] * inv);
            }
        }
    } else {
        // ================= edge branch =================
        const int bid = blockIdx.x - 512;
        const int bm = ((bid & 7) * 128 + (bid >> 3)) * 64;

        if (tid < 64) sm.e.tg[tid] = tgtp[bm + tid];

        bf16x8 zt[4], zs[4];
        #pragma unroll
        for (int u = 0; u < 4; ++u) {
            int g = u * 512 + tid;
            int r = g >> 5, c = g & 31;
            int i = bm + r;
            int tg = tgtp[i], sr = srcp[i];
            zt[u] = *reinterpret_cast<const bf16x8*>(Z + (size_t)tg * 512 + c * 8);
            zs[u] = *reinterpret_cast<const bf16x8*>(Z + (size_t)sr * 512 + 256 + c * 8);
        }
        #pragma unroll
        for (int u = 0; u < 4; ++u) {
            int g = u * 512 + tid;
            int r = g >> 5, c = g & 31;
            PU a, b, o;
            a.v = zt[u]; b.v = zs[u];
            float4 k0v = *reinterpret_cast<const float4*>(kbias + c * 8);
            float4 k1v = *reinterpret_cast<const float4*>(kbias + c * 8 + 4);
            float bb[8] = {k0v.x, k0v.y, k0v.z, k0v.w, k1v.x, k1v.y, k1v.z, k1v.w};
            #pragma unroll
            for (int j = 0; j < 8; ++j) {
                float v = __bfloat162float(a.h[j]) + __bfloat162float(b.h[j]) + bb[j];
                o.h[j] = __float2bfloat16(fmaxf(v, 0.f));
            }
            *reinterpret_cast<bf16x8*>(&sm.e.As[r * LDA + c * 8]) = o.v;
        }
        __syncthreads();

        const int wn = w;
        f32x4 acc[4][2];
        #pragma unroll
        for (int mt = 0; mt < 4; ++mt)
            #pragma unroll
            for (int nt = 0; nt < 2; ++nt)
                #pragma unroll
                for (int r = 0; r < 4; ++r) acc[mt][nt][r] = 0.f;

        #pragma unroll
        for (int k0 = 0; k0 < 256; k0 += 32) {
            bf16x8 af[4], bfr[2];
            #pragma unroll
            for (int nt = 0; nt < 2; ++nt)
                bfr[nt] = *reinterpret_cast<const bf16x8*>(
                    Bw + (size_t)(wn * 32 + nt * 16 + l16) * 256 + k0 + quad * 8);
            #pragma unroll
            for (int mt = 0; mt < 4; ++mt)
                af[mt] = *reinterpret_cast<const bf16x8*>(&sm.e.As[(mt * 16 + l16) * LDA + k0 + quad * 8]);
            #pragma unroll
            for (int mt = 0; mt < 4; ++mt)
                #pragma unroll
                for (int nt = 0; nt < 2; ++nt)
                    acc[mt][nt] = __builtin_amdgcn_mfma_f32_16x16x32_bf16(af[mt], bfr[nt], acc[mt][nt], 0, 0, 0);
        }

        __syncthreads();
        #pragma unroll
        for (int mt = 0; mt < 4; ++mt) {
            #pragma unroll
            for (int nt = 0; nt < 2; ++nt) {
                int col = wn * 32 + nt * 16 + l16;
                float bv = bias[col];
                #pragma unroll
                for (int r = 0; r < 4; ++r) {
                    int rl = mt * 16 + quad * 4 + r;
                    sm.e.As[rl * LDA + col] = __float2bfloat16(fmaxf(acc[mt][nt][r] + bv, 0.f));
                }
            }
        }
        __syncthreads();
        {
            int col = tid & 255, r0 = (tid >> 8) * 32;
            float s = 0.f;
            int cur = sm.e.tg[r0];
            #pragma unroll 8
            for (int r = 0; r < 32; ++r) {
                int rr = r0 + r;
                int t = sm.e.tg[rr];
                if (t != cur) {
                    atomicAdd(&A3f[(size_t)cur * 256 + col], s);
                    s = 0.f; cur = t;
                }
                s += __bfloat162float(sm.e.As[rr * LDA + col]);
            }
            atomicAdd(&A3f[(size_t)cur * 256 + col], s);
        }
    }
}

// ---------------------------------------------------------------------------
// Batched (grid.z) 64x64 GEMM slices: M=4096, N=256 (per slice), K=256, ldb=256.
// ---------------------------------------------------------------------------
struct GSet { const __hip_bfloat16* A; int lda; const __hip_bfloat16* B;
              const float* bias; const float* rowscale;
              const float* extra; float esc; float cscale;
              __hip_bfloat16* C; float* Cf; int vtout; int ldc; int coloff; };
struct GPack { GSet s[8]; };

__global__ __launch_bounds__(256) void gemm_bz(GPack p, const int* __restrict__ eidx)
{
    GSet g = p.s[blockIdx.z];
    constexpr int LDT = 40;
    __shared__ alignas(16) __hip_bfloat16 As[64 * LDT];
    __shared__ alignas(16) __hip_bfloat16 Bs[64 * LDT];

    const int tid = threadIdx.x;
    const int w = tid >> 6, lane = tid & 63, l16 = lane & 15, quad = lane >> 4;
    const int wm = w >> 1, wn = w & 1;
    const int bm = blockIdx.y * 64, bn = blockIdx.x * 64;

    f32x4 acc[2][2];
    #pragma unroll
    for (int i = 0; i < 2; ++i)
        #pragma unroll
        for (int j = 0; j < 2; ++j)
            #pragma unroll
            for (int r = 0; r < 4; ++r) acc[i][j][r] = 0.f;

    for (int k0 = 0; k0 < 256; k0 += 32) {
        #pragma unroll
        for (int f = tid; f < 256; f += 256) {
            int r = f >> 2, sg = f & 3;
            *reinterpret_cast<uint4*>(&As[r * LDT + sg * 8]) =
                *reinterpret_cast<const uint4*>(g.A + (size_t)(bm + r) * g.lda + k0 + sg * 8);
            *reinterpret_cast<uint4*>(&Bs[r * LDT + sg * 8]) =
                *reinterpret_cast<const uint4*>(g.B + (size_t)(bn + r) * 256 + k0 + sg * 8);
        }
        __syncthreads();
        bf16x8 af[2], bfr[2];
        #pragma unroll
        for (int mt = 0; mt < 2; ++mt)
            af[mt] = *reinterpret_cast<const bf16x8*>(&As[(wm * 32 + mt * 16 + l16) * LDT + quad * 8]);
        #pragma unroll
        for (int nt = 0; nt < 2; ++nt)
            bfr[nt] = *reinterpret_cast<const bf16x8*>(&Bs[(wn * 32 + nt * 16 + l16) * LDT + quad * 8]);
        #pragma unroll
        for (int mt = 0; mt < 2; ++mt)
            #pragma unroll
            for (int nt = 0; nt < 2; ++nt)
                acc[mt][nt] = __builtin_amdgcn_mfma_f32_16x16x32_bf16(af[mt], bfr[nt], acc[mt][nt], 0, 0, 0);
        __syncthreads();
    }

    #pragma unroll
    for (int mt = 0; mt < 2; ++mt) {
        #pragma unroll
        for (int nt = 0; nt < 2; ++nt) {
            int colL = bn + wn * 32 + nt * 16 + l16;
            #pragma unroll
            for (int r = 0; r < 4; ++r) {
                int row = bm + wm * 32 + mt * 16 + quad * 4 + r;
                float v = acc[mt][nt][r];
                if (g.bias) {
                    float bv = g.bias[colL];
                    if (g.rowscale) bv *= g.rowscale[row];
                    v += bv;
                }
                if (g.extra) v += g.esc * g.extra[(size_t)eidx[row] * QD + colL];
                v *= g.cscale;
                if (g.vtout)
                    g.C[(size_t)colL * 4096 + row] = __float2bfloat16(v);
                else if (g.Cf)
                    g.Cf[(size_t)row * g.ldc + g.coloff + colL] = v;
                else
                    g.C[(size_t)row * g.ldc + g.coloff + colL] = __float2bfloat16(v);
            }
        }
    }
}

// ---------------------------------------------------------------------------
// fp32 tiled composite-weight GEMM (startup): 32x32 tile, BK=16, 2x2 microtile.
// ---------------------------------------------------------------------------
struct FDesc { const float* A; int lda; const float* B; int ldb; int tb;
               const float* bias; float* C; int M, N, K; };
struct FPack { FDesc d[16]; };

__global__ __launch_bounds__(256) void fgemm2(FPack p)
{
    FDesc c = p.d[blockIdx.z];
    int bm = blockIdx.y * 32, bn = blockIdx.x * 32;
    if (bm >= c.M || bn >= c.N) return;
    __shared__ float As[16][33];
    __shared__ float Bs[16][33];
    int tid = threadIdx.x;
    int tr = tid / 16, tc = tid % 16;
    float acc[2][2] = {};

    for (int k0 = 0; k0 < c.K; k0 += 16) {
        #pragma unroll
        for (int u = 0; u < 2; ++u) {
            int i = tid * 2 + u;
            int m = i >> 4, kk = i & 15;
            int row = bm + m, kg = k0 + kk;
            As[kk][m] = (row < c.M && kg < c.K) ? c.A[(size_t)row * c.lda + kg] : 0.f;
        }
        if (c.tb) {
            #pragma unroll
            for (int u = 0; u < 2; ++u) {
                int i = tid * 2 + u;
                int n = i >> 4, kk = i & 15;
                int col = bn + n, kg = k0 + kk;
                Bs[kk][n] = (col < c.N && kg < c.K) ? c.B[(size_t)col * c.ldb + kg] : 0.f;
            }
        } else {
            #pragma unroll
            for (int u = 0; u < 2; ++u) {
                int i = tid * 2 + u;
                int kk = i >> 5, n = i & 31;
                int col = bn + n, kg = k0 + kk;
                Bs[kk][n] = (col < c.N && kg < c.K) ? c.B[(size_t)kg * c.ldb + col] : 0.f;
            }
        }
        __syncthreads();
        #pragma unroll
        for (int kk = 0; kk < 16; ++kk) {
            float a0 = As[kk][tr * 2], a1 = As[kk][tr * 2 + 1];
            float b0 = Bs[kk][tc * 2], b1 = Bs[kk][tc * 2 + 1];
            acc[0][0] = fmaf(a0, b0, acc[0][0]);
            acc[0][1] = fmaf(a0, b1, acc[0][1]);
            acc[1][0] = fmaf(a1, b0, acc[1][0]);
            acc[1][1] = fmaf(a1, b1, acc[1][1]);
        }
        __syncthreads();
    }

    #pragma unroll
    for (int i = 0; i < 2; ++i) {
        int row = bm + tr * 2 + i;
        if (row >= c.M) continue;
        #pragma unroll
        for (int j = 0; j < 2; ++j) {
            int col = bn + tc * 2 + j;
            if (col >= c.N) continue;
            float v = acc[i][j];
            if (c.bias) v += c.bias[col];
            c.C[(size_t)row * c.N + col] = v;
        }
    }
}

// build mask bitfield + per-target degree count in one pass
__global__ __launch_bounds__(256) void build_mask(const int* __restrict__ src,
                                                  const int* __restrict__ tgt,
                                                  unsigned* __restrict__ mb,
                                                  int* __restrict__ cnt)
{
    int e = blockIdx.x * 256 + threadIdx.x;
    if (e >= E_EDGES) return;
    int t = tgt[e];
    atomicOr(mb + (size_t)src[e] * (N_NODES / 32) + (t >> 5), 1u << (t & 31));
    atomicAdd(&cnt[t], 1);
}

__global__ __launch_bounds__(1024) void csr_scan(const int* __restrict__ cnt, int* __restrict__ off,
                                                 int* __restrict__ cursor, float* __restrict__ degf)
{
    __shared__ int sh[1024];
    int t = threadIdx.x;
    int base = t * 4;
    int c0 = cnt[base], c1 = cnt[base + 1], c2 = cnt[base + 2], c3 = cnt[base + 3];
    int sum = c0 + c1 + c2 + c3;
    sh[t] = sum; __syncthreads();
    for (int d = 1; d < 1024; d <<= 1) {
        int v = (t >= d) ? sh[t - d] : 0;
        __syncthreads();
        sh[t] += v;
        __syncthreads();
    }
    int excl = sh[t] - sum;
    int o0 = excl, o1 = excl + c0, o2 = o1 + c1, o3 = o2 + c2;
    off[base] = o0; off[base + 1] = o1; off[base + 2] = o2; off[base + 3] = o3;
    cursor[base] = o0; cursor[base + 1] = o1; cursor[base + 2] = o2; cursor[base + 3] = o3;
    degf[base] = (float)c0; degf[base + 1] = (float)c1;
    degf[base + 2] = (float)c2; degf[base + 3] = (float)c3;
    if (t == 1023) off[4096] = sh[t];
}

__global__ __launch_bounds__(256) void csr_fill(const int* __restrict__ src, const int* __restrict__ tgt,
                                                int* __restrict__ cursor,
                                                int* __restrict__ srcp, int* __restrict__ tgtp)
{
    int e = blockIdx.x * 256 + threadIdx.x;
    if (e >= E_EDGES) return;
    int t = tgt[e];
    int pos = atomicAdd(&cursor[t], 1);
    srcp[pos] = src[e];
    tgtp[pos] = t;
}

// Sparse graph-masked attention over bf16 Q,K,V. Writes out (=).
__global__ __launch_bounds__(256) void sparse_attn(
    const __hip_bfloat16* __restrict__ Q, const __hip_bfloat16* __restrict__ K,
    const __hip_bfloat16* __restrict__ V, int vld,
    const unsigned* __restrict__ maskb, float* __restrict__ outb)
{
    int i = blockIdx.x, t = threadIdx.x;
    __shared__ float qsh[256];
    __shared__ int   nb[1024];
    __shared__ float sc[1024];
    __shared__ int   cnt;
    __shared__ float red[4];
    __shared__ float smax, ssum;
    if (t == 0) cnt = 0;
    qsh[t] = __bfloat162float(Q[(size_t)i * 256 + t]);
    __syncthreads();
    if (t < 128) {
        unsigned wv = maskb[(size_t)i * 128 + t];
        while (wv) {
            int b = __ffs(wv) - 1; wv &= wv - 1;
            int p = atomicAdd(&cnt, 1);
            nb[p] = t * 32 + b;
        }
    }
    __syncthreads();
    int deg = cnt;
    int wid = t >> 6, lane = t & 63;
    if (deg > 0) {
        for (int n = wid; n < deg; n += 4) {
            union { uint2 u; __hip_bfloat16 h[4]; } kv;
            kv.u = *reinterpret_cast<const uint2*>(K + (size_t)nb[n] * 256 + lane * 4);
            float s = qsh[lane*4+0] * __bfloat162float(kv.h[0]) + qsh[lane*4+1] * __bfloat162float(kv.h[1])
                    + qsh[lane*4+2] * __bfloat162float(kv.h[2]) + qsh[lane*4+3] * __bfloat162float(kv.h[3]);
            #pragma unroll
            for (int off = 32; off; off >>= 1) s += __shfl_xor(s, off);
            if (lane == 0) sc[n] = s * 0.0625f;
        }
        __syncthreads();
        float m = -3.4e38f;
        for (int n = t; n < deg; n += 256) m = fmaxf(m, sc[n]);
        #pragma unroll
        for (int off = 32; off; off >>= 1) m = fmaxf(m, __shfl_xor(m, off));
        if (lane == 0) red[wid] = m;
        __syncthreads();
        if (t == 0) smax = fmaxf(fmaxf(red[0], red[1]), fmaxf(red[2], red[3]));
        __syncthreads();
        float ls = 0.f;
        for (int n = t; n < deg; n += 256) { float e = __expf(sc[n] - smax); sc[n] = e; ls += e; }
        #pragma unroll
        for (int off = 32; off; off >>= 1) ls += __shfl_xor(ls, off);
        if (lane == 0) red[wid] = ls;
        __syncthreads();
        if (t == 0) ssum = red[0] + red[1] + red[2] + red[3];
        __syncthreads();
        float inv = 1.f / ssum;
        float o = 0.f;
        for (int n = 0; n < deg; ++n)
            o += sc[n] * __bfloat162float(V[(size_t)nb[n] * vld + t]);
        outb[(size_t)i * 256 + t] = o * inv;
    } else {
        float o = 0.f;
        for (int j = 0; j < N_NODES; ++j) o += __bfloat162float(V[(size_t)j * vld + t]);
        outb[(size_t)i * 256 + t] = o * (1.f / N_NODES);
    }
}

// h = LN(h + a1 + a2 + a3)
__global__ __launch_bounds__(256) void ln_kernel(float* __restrict__ h, __hip_bfloat16* __restrict__ h16,
                                                 const float* __restrict__ a1,
                                                 const float* __restrict__ a2,
                                                 const float* __restrict__ a3,
                                                 const float* __restrict__ g, const float* __restrict__ b)
{
    int row = blockIdx.x, t = threadIdx.x;
    __shared__ float red[256];
    size_t off = ((size_t)row << 8) + t;
    float v = h[off] + a1[off] + a2[off] + a3[off];
    red[t] = v; __syncthreads();
    for (int s = 128; s > 0; s >>= 1) { if (t < s) red[t] += red[t + s]; __syncthreads(); }
    float mu = red[0] * (1.f / 256.f); __syncthreads();
    float d = v - mu;
    red[t] = d * d; __syncthreads();
    for (int s = 128; s > 0; s >>= 1) { if (t < s) red[t] += red[t + s]; __syncthreads(); }
    float var = red[0] * (1.f / 256.f);
    float r = d * rsqrtf(var + 1e-5f) * g[t] + b[t];
    h[off] = r;
    h16[off] = __float2bfloat16(r);
}

__global__ __launch_bounds__(256) void colpool(const float* __restrict__ h, float* __restrict__ p)
{
    int c = blockIdx.x, t = threadIdx.x;
    __shared__ float rs[256], rm[256];
    float s = 0.f, m = -3.4e38f;
    for (int row = t; row < N_NODES; row += 256) {
        float v = h[((size_t)row << 8) + c];
        s += v; m = fmaxf(m, v);
    }
    rs[t] = s; rm[t] = m; __syncthreads();
    for (int st = 128; st > 0; st >>= 1) {
        if (t < st) { rs[t] += rs[t + st]; rm[t] = fmaxf(rm[t], rm[t + st]); }
        __syncthreads();
    }
    if (t == 0) { p[c] = rs[0] * (1.f / N_NODES); p[256 + c] = rm[0]; }
}

__global__ __launch_bounds__(256) void classifier(const float* __restrict__ pooled,
                                                  const float* __restrict__ Wc1, const float* __restrict__ bc1,
                                                  const float* __restrict__ Wc2, const float* __restrict__ bc2,
                                                  float* __restrict__ out)
{
    __shared__ float p[512];
    __shared__ float z[256];
    int t = threadIdx.x;
    p[t] = pooled[t]; p[256 + t] = pooled[256 + t];
    __syncthreads();
    float s = bc1[t];
    for (int k = 0; k < 512; ++k) s = fmaf(p[k], Wc1[k * 256 + t], s);
    z[t] = fmaxf(s, 0.f);
    __syncthreads();
    if (t < OUT_F) {
        float o = bc2[t];
        for (int j = 0; j < 256; ++j) o = fmaf(z[j], Wc2[j * OUT_F + t], o);
        out[t] = o;
    }
}

// ---- bf16 conversion ----
struct CDesc { const float* s; __hip_bfloat16* d; int total; };
struct CPack { CDesc d[2]; };
__global__ __launch_bounds__(256) void convert_copy(CPack p)
{
    CDesc c = p.d[blockIdx.y];
    for (int i = blockIdx.x * 256 + threadIdx.x; i < c.total; i += gridDim.x * 256)
        c.d[i] = __float2bfloat16(c.s[i]);
}
// LDS-tiled transpose-convert: d[n*K+k] = bf16(s[k*sld+n]); coalesced both sides
struct TDesc { const float* s; __hip_bfloat16* d; int K, N, sld; };
struct TPack { TDesc d[23]; };
__global__ __launch_bounds__(256) void convert_t32(TPack p)
{
    TDesc c = p.d[blockIdx.z];
    int k0 = blockIdx.x * 32, n0 = blockIdx.y * 32;
    if (k0 >= c.K || n0 >= c.N) return;
    __shared__ float t[32][33];
    int tr = threadIdx.x >> 5, tc = threadIdx.x & 31;
    #pragma unroll
    for (int rr = 0; rr < 32; rr += 8)
        t[tc][tr + rr] = c.s[(size_t)(k0 + tr + rr) * c.sld + n0 + tc];
    __syncthreads();
    #pragma unroll
    for (int rr = 0; rr < 32; rr += 8)
        c.d[(size_t)(n0 + tr + rr) * c.K + k0 + tc] = __float2bfloat16(t[tr + rr][tc]);
}

extern "C" void kernel_launch(void* const* d_in, const int* in_sizes, int n_in,
                              void* d_out, int out_size, void* d_ws, size_t ws_size,
                              hipStream_t stream)
{
    const float* x    = (const float*)d_in[0];
    const int*   ei   = (const int*)d_in[1];
    const int*   ct   = (const int*)d_in[2];
    const float* Wi   = (const float*)d_in[3];
    const float* bi   = (const float*)d_in[4];
    const float* Wq   = (const float*)d_in[5];
    const float* bq   = (const float*)d_in[6];
    const float* Wk   = (const float*)d_in[7];
    const float* bk   = (const float*)d_in[8];
    const float* Wv   = (const float*)d_in[9];
    const float* bv   = (const float*)d_in[10];
    const float* Bc   = (const float*)d_in[11];
    const float* cemb = (const float*)d_in[12];
    const float* Win  = (const float*)d_in[13];
    const float* binp = (const float*)d_in[14];
    const float* Wo   = (const float*)d_in[15];
    const float* bo   = (const float*)d_in[16];
    const float* Wm1  = (const float*)d_in[17];
    const float* bm1  = (const float*)d_in[18];
    const float* Wm2  = (const float*)d_in[19];
    const float* bm2  = (const float*)d_in[20];
    const float* Wm3  = (const float*)d_in[21];
    const float* bm3  = (const float*)d_in[22];
    const float* lng  = (const float*)d_in[23];
    const float* lnb  = (const float*)d_in[24];
    const float* Wc1  = (const float*)d_in[25];
    const float* bc1  = (const float*)d_in[26];
    const float* Wc2  = (const float*)d_in[27];
    const float* bc2  = (const float*)d_in[28];

    const int* src = ei;
    const int* tgt = ei + E_EDGES;

    // ---- workspace carve-up ----
    char* wp = (char*)d_ws;
    auto alloc = [&](size_t bytes) { char* r = wp; wp += (bytes + 255) & ~(size_t)255; return r; };
    const size_t NH = (size_t)N_NODES * 256;
    float* h      = (float*)alloc(NH * 4);
    float* a1     = (float*)alloc(NH * 4);
    float* a2     = (float*)alloc(NH * 4);
    float* a3     = (float*)alloc(NH * 4);
    float* pooled = (float*)alloc(512 * 4);
    float* degf   = (float*)alloc(N_NODES * 4);
    float* A3f    = (float*)alloc(NH * 4);   // fused edge seg-sum accumulator
    __hip_bfloat16* x16 = (__hip_bfloat16*)alloc((size_t)N_NODES * 512 * 2);
    __hip_bfloat16* h16 = (__hip_bfloat16*)alloc(NH * 2);
    __hip_bfloat16* Qb  = (__hip_bfloat16*)alloc(NH * 2);
    __hip_bfloat16* Kb  = (__hip_bfloat16*)alloc(NH * 2);
    __hip_bfloat16* Vb  = (__hip_bfloat16*)alloc(NH * 2);
    __hip_bfloat16* Tq  = (__hip_bfloat16*)alloc(NH * 2);
    __hip_bfloat16* Tk  = (__hip_bfloat16*)alloc(NH * 2);
    __hip_bfloat16* Vt  = (__hip_bfloat16*)alloc(NH * 2);
    __hip_bfloat16* Z12 = (__hip_bfloat16*)alloc((size_t)N_NODES * 512 * 2);
    __hip_bfloat16* A3  = (__hip_bfloat16*)alloc(NH * 2);
    __hip_bfloat16* Wi_t= (__hip_bfloat16*)alloc((size_t)256 * 512 * 2);
    // fp32 composite weights / biases / ce-tables, per layer
    float *Wqc_f[2], *Wkc_f[2], *Wqm_f[2], *Wkm_f[2], *Wvm_f[2];
    float *bqc[2], *bkc[2], *bqm[2], *bkm[2], *bvm[2], *ceq2[2], *cek2[2];
    for (int l = 0; l < 2; ++l) {
        Wqc_f[l] = (float*)alloc(65536 * 4); Wkc_f[l] = (float*)alloc(65536 * 4);
        Wqm_f[l] = (float*)alloc(65536 * 4); Wkm_f[l] = (float*)alloc(65536 * 4);
        Wvm_f[l] = (float*)alloc(65536 * 4);
        bqc[l] = (float*)alloc(256 * 4); bkc[l] = (float*)alloc(256 * 4);
        bqm[l] = (float*)alloc(256 * 4); bkm[l] = (float*)alloc(256 * 4);
        bvm[l] = (float*)alloc(256 * 4);
        ceq2[l] = (float*)alloc(CT_N * 256 * 4); cek2[l] = (float*)alloc(CT_N * 256 * 4);
    }
    // bf16 [N][K] weights: per layer: Wqc,Wkc,Wqm,Wkm,Wvm,Wv,Wo,Wm1a,Wm1b,Wm2,Wm3
    __hip_bfloat16* WB[2][11];
    for (int l = 0; l < 2; ++l)
        for (int m = 0; m < 11; ++m)
            WB[l][m] = (__hip_bfloat16*)alloc(65536 * 2);
    unsigned* maskb = (unsigned*)alloc((size_t)N_NODES * 128 * 4);
    int* cnt    = (int*)alloc(N_NODES * 4);
    int* cursor = (int*)alloc(N_NODES * 4);
    int* off    = (int*)alloc((N_NODES + 1) * 4);
    int* srcp   = (int*)alloc(E_EDGES * 4);
    int* tgtp   = (int*)alloc(E_EDGES * 4);

    // ---- startup: x conversion ----
    CPack cp; cp.d[0] = {x, x16, N_NODES * 512};
    convert_copy<<<dim3(256, 1), 256, 0, stream>>>(cp);

    // ---- composite fp32 weights (tiled fgemm2, 2 dependent waves) ----
    FPack f1; int n1 = 0;
    FPack f2; int n2 = 0;
    for (int l = 0; l < 2; ++l) {
        const float* Wq_l  = Wq + (size_t)l * 65536;
        const float* Wk_l  = Wk + (size_t)l * 65536;
        const float* Wv_l  = Wv + (size_t)l * 65536;
        const float* Bc_l  = Bc + (size_t)l * 65536;
        const float* Win_l = Win + (size_t)l * 256 * 768;
        const float* ce_l  = cemb + (size_t)l * CT_N * QD;
        const float* bq_l  = bq + l * 256;
        const float* bk_l  = bk + l * 256;
        const float* bv_l  = bv + l * 256;
        const float* bin_l = binp + l * 768;
        f1.d[n1++] = {Wq_l, 256, Bc_l, 256, 0, nullptr, Wqc_f[l], 256, 256, 256};
        f1.d[n1++] = {Wk_l, 256, Bc_l, 256, 1, nullptr, Wkc_f[l], 256, 256, 256};
        f1.d[n1++] = {bq_l, 256, Bc_l, 256, 0, nullptr, bqc[l], 1, 256, 256};
        f1.d[n1++] = {bk_l, 256, Bc_l, 256, 1, nullptr, bkc[l], 1, 256, 256};
        f2.d[n2++] = {Wqc_f[l], 256, Win_l,       768, 0, nullptr, Wqm_f[l], 256, 256, 256};
        f2.d[n2++] = {Wkc_f[l], 256, Win_l + 256, 768, 0, nullptr, Wkm_f[l], 256, 256, 256};
        f2.d[n2++] = {Wv_l,     256, Win_l + 512, 768, 0, nullptr, Wvm_f[l], 256, 256, 256};
        f2.d[n2++] = {ce_l,     256, Win_l,       768, 0, nullptr, ceq2[l], CT_N, 256, 256};
        f2.d[n2++] = {ce_l,     256, Win_l + 256, 768, 0, nullptr, cek2[l], CT_N, 256, 256};
        f2.d[n2++] = {bqc[l],   256, Win_l,       768, 0, bin_l,       bqm[l], 1, 256, 256};
        f2.d[n2++] = {bkc[l],   256, Win_l + 256, 768, 0, bin_l + 256, bkm[l], 1, 256, 256};
        f2.d[n2++] = {bv_l,     256, Win_l + 512, 768, 0, bin_l + 512, bvm[l], 1, 256, 256};
    }
    fgemm2<<<dim3(8, 8, n1), 256, 0, stream>>>(f1);
    fgemm2<<<dim3(8, 8, n2), 256, 0, stream>>>(f2);

    // ---- transpose-convert all [K][N] fp32 weights to bf16 [N][K] ----
    TPack tp; int ndt = 0;
    auto addT = [&](const float* s, __hip_bfloat16* d, int K, int N, int sld) { tp.d[ndt++] = {s, d, K, N, sld}; };
    addT(Wi, Wi_t, 512, 256, 256);
    for (int l = 0; l < 2; ++l) {
        const float* Wv_l  = Wv + (size_t)l * 65536;
        const float* Wo_l  = Wo + (size_t)l * 65536;
        const float* Wm1_l = Wm1 + (size_t)l * (2 * H_F + QD) * QD;  // layer stride 768*256!
        const float* Wm2_l = Wm2 + (size_t)l * 65536;
        const float* Wm3_l = Wm3 + (size_t)l * 65536;
        addT(Wqc_f[l], WB[l][0], 256, 256, 256);
        addT(Wkc_f[l], WB[l][1], 256, 256, 256);
        addT(Wqm_f[l], WB[l][2], 256, 256, 256);
        addT(Wkm_f[l], WB[l][3], 256, 256, 256);
        addT(Wvm_f[l], WB[l][4], 256, 256, 256);
        addT(Wv_l,     WB[l][5], 256, 256, 256);
        addT(Wo_l,     WB[l][6], 256, 256, 256);
        addT(Wm1_l,             WB[l][7], 256, 256, 256);
        addT(Wm1_l + 256 * 256, WB[l][8], 256, 256, 256);
        addT(Wm2_l,    WB[l][9],  256, 256, 256);
        addT(Wm3_l,    WB[l][10], 256, 256, 256);
    }
    convert_t32<<<dim3(16, 8, ndt), 256, 0, stream>>>(tp);

    hipMemsetAsync(maskb, 0, (size_t)N_NODES * 128 * 4, stream);
    hipMemsetAsync(cnt, 0, N_NODES * 4, stream);
    build_mask<<<E_EDGES / 256, 256, 0, stream>>>(src, tgt, maskb, cnt);
    csr_scan<<<1, 1024, 0, stream>>>(cnt, off, cursor, degf);
    csr_fill<<<E_EDGES / 256, 256, 0, stream>>>(src, tgt, cursor, srcp, tgtp);

    // h = relu(x @ Wi + bi)
    gemm_mfma<64, 64, false><<<dim3(4, 64), 256, 0, stream>>>(
        x16, 512, Wi_t, 512, h, h16, 256, 512,
        bi, nullptr, nullptr, nullptr, nullptr, FLAG_RELU | FLAG_WF32 | FLAG_WB16);

    const float QSCALE = 0.25507693f;   // log2(e)/sqrt(32)

    for (int l = 0; l < L_LAYERS; ++l) {
        const float* ce_l  = cemb + (size_t)l * CT_N * QD;
        const float* bo_l  = bo + l * QD;
        const float* bm1_l = bm1 + l * QD;
        const float* bm2_l = bm2 + l * QD;
        const float* bm3_l = bm3 + l * H_F;
        const float* lng_l = lng + l * H_F;
        const float* lnb_l = lnb + l * H_F;
        const float* bv_l  = bv + l * 256;

        // ---- one z=8 projection launch from h ----
        {
            GPack gp;
            gp.s[0] = {h16, 256, WB[l][0], bqc[l], nullptr, ce_l,    0.1f, 1.0f,   Qb,  nullptr, 0, 256, 0};
            gp.s[1] = {h16, 256, WB[l][1], bkc[l], nullptr, ce_l,    0.1f, 1.0f,   Kb,  nullptr, 0, 256, 0};
            gp.s[2] = {h16, 256, WB[l][5], bv_l,   nullptr, nullptr, 0.f,  1.0f,   Vb,  nullptr, 0, 256, 0};
            gp.s[3] = {h16, 256, WB[l][2], bqm[l], nullptr, ceq2[l], 0.1f, QSCALE, Tq,  nullptr, 0, 256, 0};
            gp.s[4] = {h16, 256, WB[l][3], bkm[l], nullptr, cek2[l], 0.1f, 1.0f,   Tk,  nullptr, 0, 256, 0};
            gp.s[5] = {h16, 256, WB[l][4], bvm[l], nullptr, nullptr, 0.f,  1.0f,   Vt,  nullptr, 1, 256, 0};
            gp.s[6] = {h16, 256, WB[l][7], nullptr, nullptr, nullptr, 0.f, 1.0f,   Z12, nullptr, 0, 512, 0};
            gp.s[7] = {h16, 256, WB[l][8], nullptr, nullptr, nullptr, 0.f, 1.0f,   Z12, nullptr, 0, 512, 256};
            gemm_bz<<<dim3(4, 64, 8), 256, 0, stream>>>(gp, ct);
        }

        // zero the fused seg-sum accumulator (4MB, <1us)
        hipMemsetAsync(A3f, 0, NH * 4, stream);

        // sparse graph-masked attention -> a1
        sparse_attn<<<N_NODES, 256, 0, stream>>>(Qb, Kb, Vb, 256, maskb, a1);

        // fused flash-MHA (blocks 0-511) + edge-MLP/seg-sum (blocks 512-1535)
        mha_edge_fused<<<1536, 512, 0, stream>>>(
            Tq, Tk, Vt, Qb, Z12, WB[l][9], A3f, tgtp, srcp, bm1_l, bm2_l);
        {
            CPack c2; c2.d[0] = {A3f, A3, (int)NH};
            convert_copy<<<dim3(256, 1), 256, 0, stream>>>(c2);
        }

        // batched fp32 outputs: a2 = heads@Wo + bo ; a3 = A3@Wm3 + deg*bm3
        {
            GPack gp;
            gp.s[0] = {Qb, 256, WB[l][6],  bo_l,  nullptr, nullptr, 0.f, 1.0f, nullptr, a2, 0, 256, 0};
            gp.s[1] = {A3, 256, WB[l][10], bm3_l, degf,    nullptr, 0.f, 1.0f, nullptr, a3, 0, 256, 0};
            gemm_bz<<<dim3(4, 64, 2), 256, 0, stream>>>(gp, ct);
        }

        // h = LN(h + a1 + a2 + a3)
        ln_kernel<<<N_NODES, 256, 0, stream>>>(h, h16, a1, a2, a3, lng_l, lnb_l);
    }

    colpool<<<H_F, 256, 0, stream>>>(h, pooled);
    classifier<<<1, 256, 0, stream>>>(pooled, Wc1, bc1, Wc2, bc2, (float*)d_out);
}